// Round 1
// baseline (423.510 us; speedup 1.0000x reference)
//
#include <hip/hip_runtime.h>
#include <math.h>

typedef __bf16 bf16_t;
typedef __bf16 bf16x8 __attribute__((ext_vector_type(8)));
typedef float f32x4 __attribute__((ext_vector_type(4)));

#define B_    2
#define LQ    4096
#define LK    1024
#define QDIM  2048
#define KVDIM 2048
#define H_    16
#define HD_   128
#define KVC_  512
#define QC_   768
#define R_    64

typedef __attribute__((address_space(1))) void gvoid_t;
typedef __attribute__((address_space(3))) void lvoid_t;

static __device__ __forceinline__ void gld_lds16(const void* g, void* l) {
  __builtin_amdgcn_global_load_lds((gvoid_t*)(void*)g, (lvoid_t*)l, 16, 0, 0);
}

// ---------------- fp32 -> bf16 convert (vectorized) ----------------
__global__ void cvt_f32_bf16(const float* __restrict__ in, bf16_t* __restrict__ out, long n) {
  long i = ((long)blockIdx.x * blockDim.x + threadIdx.x) * 8;
  const long stride = (long)gridDim.x * blockDim.x * 8;
  for (; i < n; i += stride) {
    float4 a = *(const float4*)(in + i);
    float4 b = *(const float4*)(in + i + 4);
    bf16x8 t;
    t[0] = (bf16_t)a.x; t[1] = (bf16_t)a.y; t[2] = (bf16_t)a.z; t[3] = (bf16_t)a.w;
    t[4] = (bf16_t)b.x; t[5] = (bf16_t)b.y; t[6] = (bf16_t)b.z; t[7] = (bf16_t)b.w;
    *(bf16x8*)(out + i) = t;
  }
}

// ---------------- transpose + convert: in (K x N) fp32 -> out (N x K) bf16 ----------------
__global__ void transpose_cvt(const float* __restrict__ in, bf16_t* __restrict__ out, int K, int N) {
  __shared__ float t[32][33];
  const int bx = blockIdx.x * 32, by = blockIdx.y * 32;
  const int x = threadIdx.x, y = threadIdx.y;
#pragma unroll
  for (int j = 0; j < 32; j += 8) {
    int k = by + y + j, nn = bx + x;
    if (k < K && nn < N) t[y + j][x] = in[(size_t)k * N + nn];
  }
  __syncthreads();
#pragma unroll
  for (int j = 0; j < 32; j += 8) {
    int nn = bx + y + j, k = by + x;
    if (nn < N && k < K) out[(size_t)nn * K + k] = (bf16_t)t[x][y + j];
  }
}

// ---------------- bf16 MFMA GEMM: C[M,N] = A[M,K] @ Bt[N,K]^T ----------------
// A, Bt bf16 row-major; C = fp32 or bf16. 128x128 tile, BK=64, 4 waves.
template <typename CT>
__global__ __launch_bounds__(256) void gemm_bt(
    const bf16_t* __restrict__ A, const bf16_t* __restrict__ Bt,
    CT* __restrict__ C, int M, int N, int K) {
  __shared__ __align__(16) bf16_t lA[128 * 64];
  __shared__ __align__(16) bf16_t lB[128 * 64];
  const int tid = threadIdx.x;
  const int wave = tid >> 6, lane = tid & 63;
  const int row0 = blockIdx.y * 128, col0 = blockIdx.x * 128;
  const int wr = (wave >> 1) * 64, wc = (wave & 1) * 64;
  f32x4 acc[4][4] = {};
  const int kT = K >> 6;
  const int lr = lane >> 3;          // row within 8-row chunk
  const int lc8 = (lane & 7) * 8;    // col (elements) within 64-wide K slab

  for (int kt = 0; kt < kT; ++kt) {
    const int k0 = kt << 6;
    __syncthreads();  // previous compute done before overwrite
#pragma unroll
    for (int j = 0; j < 4; ++j) {
      const int c = wave * 4 + j;    // chunk 0..15, 8 rows each
      const bf16_t* ga = A + (size_t)(row0 + c * 8 + lr) * K + k0 + lc8;
      gld_lds16(ga, &lA[c * 512]);
      const bf16_t* gb = Bt + (size_t)(col0 + c * 8 + lr) * K + k0 + lc8;
      gld_lds16(gb, &lB[c * 512]);
    }
    __syncthreads();  // staging visible
#pragma unroll
    for (int kk = 0; kk < 2; ++kk) {
      bf16x8 af[4], bfr[4];
      const int kc = kk * 32 + (lane >> 4) * 8;
      const int fr = lane & 15;
#pragma unroll
      for (int m = 0; m < 4; ++m)
        af[m] = *(const bf16x8*)&lA[(wr + m * 16 + fr) * 64 + kc];
#pragma unroll
      for (int n = 0; n < 4; ++n)
        bfr[n] = *(const bf16x8*)&lB[(wc + n * 16 + fr) * 64 + kc];
#pragma unroll
      for (int m = 0; m < 4; ++m)
#pragma unroll
        for (int n = 0; n < 4; ++n)
          acc[m][n] = __builtin_amdgcn_mfma_f32_16x16x32_bf16(af[m], bfr[n], acc[m][n], 0, 0, 0);
    }
  }
  const int fr = lane & 15, fq = lane >> 4;
#pragma unroll
  for (int m = 0; m < 4; ++m)
#pragma unroll
    for (int n = 0; n < 4; ++n) {
      const int col = col0 + wc + n * 16 + fr;
#pragma unroll
      for (int r = 0; r < 4; ++r) {
        const int row = row0 + wr + m * 16 + fq * 4 + r;
        C[(size_t)row * N + col] = (CT)acc[m][n][r];
      }
    }
}

// ---------------- RoPE on q_rope (in place, bf16), pos = query index ----------------
__global__ __launch_bounds__(256) void qrope_kernel(bf16_t* __restrict__ x) {
  const long row = (long)blockIdx.x * 8 + (threadIdx.x >> 5);  // (b*LQ + q)*H + h
  const int i = threadIdx.x & 31;
  const int q = (int)((row >> 4) & (LQ - 1));  // row/H % LQ
  bf16_t* p = x + row * R_;
  const float x1 = (float)p[i], x2 = (float)p[i + 32];
  const float invf = expf(-((float)i / 32.f) * logf(10000.f));
  float sn, cs;
  sincosf((float)q * invf, &sn, &cs);
  p[i]      = (bf16_t)(x1 * cs - x2 * sn);
  p[i + 32] = (bf16_t)(x1 * sn + x2 * cs);
}

// ---------------- k_rope = rope(kv_c @ W_kr), fused, pos = key index ----------------
__global__ __launch_bounds__(64) void krope_kernel(
    const bf16_t* __restrict__ kvc, const float* __restrict__ Wkr, bf16_t* __restrict__ kr) {
  __shared__ float rowb[KVC_];
  __shared__ float dots[R_];
  const int row = blockIdx.x;       // b*LK + ki
  const int ki = row & (LK - 1);
  const int c = threadIdx.x;        // 0..63
  const bf16_t* rp = kvc + (size_t)row * KVC_;
  for (int i = c; i < KVC_; i += 64) rowb[i] = (float)rp[i];
  __syncthreads();
  float s = 0.f;
  for (int k = 0; k < KVC_; ++k) s += rowb[k] * Wkr[k * R_ + c];
  dots[c] = s;
  __syncthreads();
  if (c < 32) {
    const float x1 = dots[c], x2 = dots[c + 32];
    const float invf = expf(-((float)c / 32.f) * logf(10000.f));
    float sn, cs;
    sincosf((float)ki * invf, &sn, &cs);
    kr[(size_t)row * R_ + c]      = (bf16_t)(x1 * cs - x2 * sn);
    kr[(size_t)row * R_ + 32 + c] = (bf16_t)(x1 * sn + x2 * cs);
  }
}

// ---------------- sparse windowed attention: <=9 keys per query ----------------
// 1 wave per query row; 4 lanes per head (16 heads). fp32 math from bf16 inputs.
__global__ __launch_bounds__(256) void attn_sparse(
    const bf16_t* __restrict__ qn, const bf16_t* __restrict__ qr,
    const bf16_t* __restrict__ kn, const bf16_t* __restrict__ kr,
    const bf16_t* __restrict__ vv, const int* __restrict__ seg,
    bf16_t* __restrict__ out) {
  const int qrow = blockIdx.x * 4 + (threadIdx.x >> 6);  // b*LQ + qi
  const int lane = threadIdx.x & 63;
  const int h = lane >> 2, sub = lane & 3;
  const int b = qrow >> 12;  // / LQ
  const int s = seg[qrow];
  const int kl = max(0, s - 8);
  const float scale = 0.07216878364870322f;  // 1/sqrt(HD+R)

  float qnf[32], qrf[16];
  {
    const bf16_t* p = qn + (size_t)qrow * (H_ * HD_) + h * HD_ + sub * 32;
#pragma unroll
    for (int j = 0; j < 4; ++j) {
      bf16x8 t = *(const bf16x8*)(p + j * 8);
#pragma unroll
      for (int e = 0; e < 8; ++e) qnf[j * 8 + e] = (float)t[e];
    }
    const bf16_t* p2 = qr + (size_t)qrow * (H_ * R_) + h * R_ + sub * 16;
#pragma unroll
    for (int j = 0; j < 2; ++j) {
      bf16x8 t = *(const bf16x8*)(p2 + j * 8);
#pragma unroll
      for (int e = 0; e < 8; ++e) qrf[j * 8 + e] = (float)t[e];
    }
  }

  float sc[9];
#pragma unroll
  for (int kk = 0; kk < 9; ++kk) {
    const int kx = kl + kk;             // always < LK (kl+8 <= max(s,8) <= LK-1.. safe)
    const int krow = b * LK + kx;
    float d = 0.f;
    const bf16_t* p = kn + (size_t)krow * (H_ * HD_) + h * HD_ + sub * 32;
#pragma unroll
    for (int j = 0; j < 4; ++j) {
      bf16x8 t = *(const bf16x8*)(p + j * 8);
#pragma unroll
      for (int e = 0; e < 8; ++e) d += qnf[j * 8 + e] * (float)t[e];
    }
    const bf16_t* p2 = kr + (size_t)krow * R_ + sub * 16;
#pragma unroll
    for (int j = 0; j < 2; ++j) {
      bf16x8 t = *(const bf16x8*)(p2 + j * 8);
#pragma unroll
      for (int e = 0; e < 8; ++e) d += qrf[j * 8 + e] * (float)t[e];
    }
    d += __shfl_xor(d, 1);
    d += __shfl_xor(d, 2);
    sc[kk] = (kx <= s) ? d * scale : -1e30f;
  }
  float m = sc[0];
#pragma unroll
  for (int kk = 1; kk < 9; ++kk) m = fmaxf(m, sc[kk]);
  float sum = 0.f;
#pragma unroll
  for (int kk = 0; kk < 9; ++kk) { const float p = expf(sc[kk] - m); sc[kk] = p; sum += p; }
  const float inv = 1.f / sum;

  float o[32];
#pragma unroll
  for (int j = 0; j < 32; ++j) o[j] = 0.f;
#pragma unroll
  for (int kk = 0; kk < 9; ++kk) {
    const int krow = b * LK + kl + kk;
    const float p = sc[kk] * inv;
    const bf16_t* pv = vv + (size_t)krow * (H_ * HD_) + h * HD_ + sub * 32;
#pragma unroll
    for (int j = 0; j < 4; ++j) {
      bf16x8 t = *(const bf16x8*)(pv + j * 8);
#pragma unroll
      for (int e = 0; e < 8; ++e) o[j * 8 + e] += p * (float)t[e];
    }
  }
  bf16_t* po = out + (size_t)qrow * (H_ * HD_) + h * HD_ + sub * 32;
#pragma unroll
  for (int j = 0; j < 4; ++j) {
    bf16x8 t;
#pragma unroll
    for (int e = 0; e < 8; ++e) t[e] = (bf16_t)o[j * 8 + e];
    *(bf16x8*)(po + j * 8) = t;
  }
}

extern "C" void kernel_launch(void* const* d_in, const int* in_sizes, int n_in,
                              void* d_out, int out_size, void* d_ws, size_t ws_size,
                              hipStream_t stream) {
  const float* q     = (const float*)d_in[0];
  const float* kv    = (const float*)d_in[1];
  const int*   seg   = (const int*)d_in[2];
  const float* W_kvc = (const float*)d_in[3];
  const float* W_dq  = (const float*)d_in[4];
  const float* W_uq  = (const float*)d_in[5];
  const float* W_qr  = (const float*)d_in[6];
  const float* W_uk  = (const float*)d_in[7];
  const float* W_kr  = (const float*)d_in[8];
  const float* W_uv  = (const float*)d_in[9];
  const float* W_o   = (const float*)d_in[10];
  float* out = (float*)d_out;
  (void)in_sizes; (void)n_in; (void)out_size; (void)ws_size;

  char* ws = (char*)d_ws;
  size_t off = 0;
  auto alloc = [&](size_t bytes) {
    char* p = ws + off;
    off = (off + bytes + 255) & ~(size_t)255;
    return p;
  };
  bf16_t* q_bf   = (bf16_t*)alloc((size_t)B_ * LQ * QDIM * 2);   // reused as q_nope
  bf16_t* kv_bf  = (bf16_t*)alloc((size_t)B_ * LK * KVDIM * 2);  // reused as k_nope
  bf16_t* WkvcT  = (bf16_t*)alloc((size_t)KVC_ * KVDIM * 2);
  bf16_t* WdqT   = (bf16_t*)alloc((size_t)QC_ * QDIM * 2);
  bf16_t* WuqT   = (bf16_t*)alloc((size_t)(H_ * HD_) * QC_ * 2);
  bf16_t* WqrT   = (bf16_t*)alloc((size_t)(H_ * R_) * QC_ * 2);
  bf16_t* WukT   = (bf16_t*)alloc((size_t)(H_ * HD_) * KVC_ * 2);
  bf16_t* WuvT   = (bf16_t*)alloc((size_t)(H_ * HD_) * KVC_ * 2);
  bf16_t* WoT    = (bf16_t*)alloc((size_t)QDIM * (H_ * HD_) * 2);
  bf16_t* kv_c   = (bf16_t*)alloc((size_t)B_ * LK * KVC_ * 2);
  bf16_t* q_c    = (bf16_t*)alloc((size_t)B_ * LQ * QC_ * 2);    // reused as v
  bf16_t* q_rope = (bf16_t*)alloc((size_t)B_ * LQ * H_ * R_ * 2);
  bf16_t* kr     = (bf16_t*)alloc((size_t)B_ * LK * R_ * 2);
  bf16_t* attn_o = (bf16_t*)alloc((size_t)B_ * LQ * H_ * HD_ * 2);
  bf16_t* q_nope = q_bf;   // q_bf dead after q_c GEMM
  bf16_t* k_nope = kv_bf;  // kv_bf dead after kv_c GEMM
  bf16_t* v_buf  = q_c;    // q_c dead after q_nope/q_rope GEMMs

  // ---- convert inputs to bf16 ----
  cvt_f32_bf16<<<4096, 256, 0, stream>>>(q, q_bf, (long)B_ * LQ * QDIM);
  cvt_f32_bf16<<<2048, 256, 0, stream>>>(kv, kv_bf, (long)B_ * LK * KVDIM);
  const dim3 tb(32, 8);
  transpose_cvt<<<dim3(KVC_ / 32, KVDIM / 32), tb, 0, stream>>>(W_kvc, WkvcT, KVDIM, KVC_);
  transpose_cvt<<<dim3(QC_ / 32, QDIM / 32), tb, 0, stream>>>(W_dq, WdqT, QDIM, QC_);
  transpose_cvt<<<dim3((H_ * HD_) / 32, QC_ / 32), tb, 0, stream>>>(W_uq, WuqT, QC_, H_ * HD_);
  transpose_cvt<<<dim3((H_ * R_) / 32, QC_ / 32), tb, 0, stream>>>(W_qr, WqrT, QC_, H_ * R_);
  transpose_cvt<<<dim3((H_ * HD_) / 32, KVC_ / 32), tb, 0, stream>>>(W_uk, WukT, KVC_, H_ * HD_);
  transpose_cvt<<<dim3((H_ * HD_) / 32, KVC_ / 32), tb, 0, stream>>>(W_uv, WuvT, KVC_, H_ * HD_);
  transpose_cvt<<<dim3(QDIM / 32, (H_ * HD_) / 32), tb, 0, stream>>>(W_o, WoT, H_ * HD_, QDIM);

  // ---- projection GEMMs (C = A @ Bt^T) ----
  gemm_bt<bf16_t><<<dim3(KVC_ / 128, (B_ * LK) / 128), 256, 0, stream>>>(
      kv_bf, WkvcT, kv_c, B_ * LK, KVC_, KVDIM);
  gemm_bt<bf16_t><<<dim3(QC_ / 128, (B_ * LQ) / 128), 256, 0, stream>>>(
      q_bf, WdqT, q_c, B_ * LQ, QC_, QDIM);
  gemm_bt<bf16_t><<<dim3((H_ * HD_) / 128, (B_ * LQ) / 128), 256, 0, stream>>>(
      q_c, WuqT, q_nope, B_ * LQ, H_ * HD_, QC_);
  gemm_bt<bf16_t><<<dim3((H_ * R_) / 128, (B_ * LQ) / 128), 256, 0, stream>>>(
      q_c, WqrT, q_rope, B_ * LQ, H_ * R_, QC_);
  qrope_kernel<<<(B_ * LQ * H_) / 8, 256, 0, stream>>>(q_rope);
  gemm_bt<bf16_t><<<dim3((H_ * HD_) / 128, (B_ * LK) / 128), 256, 0, stream>>>(
      kv_c, WukT, k_nope, B_ * LK, H_ * HD_, KVC_);
  gemm_bt<bf16_t><<<dim3((H_ * HD_) / 128, (B_ * LK) / 128), 256, 0, stream>>>(
      kv_c, WuvT, v_buf, B_ * LK, H_ * HD_, KVC_);
  krope_kernel<<<B_ * LK, 64, 0, stream>>>(kv_c, W_kr, kr);

  // ---- sparse attention (<=9 keys/query) ----
  attn_sparse<<<(B_ * LQ) / 4, 256, 0, stream>>>(q_nope, q_rope, k_nope, kr, v_buf, seg, attn_o);

  // ---- output projection ----
  gemm_bt<float><<<dim3(QDIM / 128, (B_ * LQ) / 128), 256, 0, stream>>>(
      attn_o, WoT, out, B_ * LQ, QDIM, H_ * HD_);
}

// Round 2
// 407.376 us; speedup vs baseline: 1.0396x; 1.0396x over previous
//
#include <hip/hip_runtime.h>
#include <math.h>

typedef __bf16 bf16_t;
typedef __bf16 bf16x8 __attribute__((ext_vector_type(8)));
typedef float f32x4 __attribute__((ext_vector_type(4)));

#define B_    2
#define LQ    4096
#define LK    1024
#define QDIM  2048
#define KVDIM 2048
#define H_    16
#define HD_   128
#define KVC_  512
#define QC_   768
#define R_    64

// fused row widths
#define QCOMB 3072   // [q_nope(2048) | q_rope(1024)]
#define KCOMB 4224   // [k_nope(2048) | v(2048) | k_rope(64) | pad(64)]

typedef __attribute__((address_space(1))) void gvoid_t;
typedef __attribute__((address_space(3))) void lvoid_t;

static __device__ __forceinline__ void gld_lds16(const void* g, void* l) {
  __builtin_amdgcn_global_load_lds((gvoid_t*)(void*)g, (lvoid_t*)l, 16, 0, 0);
}

// ---------------- fp32 -> bf16 convert (vectorized) ----------------
__global__ void cvt_f32_bf16(const float* __restrict__ in, bf16_t* __restrict__ out, long n) {
  long i = ((long)blockIdx.x * blockDim.x + threadIdx.x) * 8;
  const long stride = (long)gridDim.x * blockDim.x * 8;
  for (; i < n; i += stride) {
    float4 a = *(const float4*)(in + i);
    float4 b = *(const float4*)(in + i + 4);
    bf16x8 t;
    t[0] = (bf16_t)a.x; t[1] = (bf16_t)a.y; t[2] = (bf16_t)a.z; t[3] = (bf16_t)a.w;
    t[4] = (bf16_t)b.x; t[5] = (bf16_t)b.y; t[6] = (bf16_t)b.z; t[7] = (bf16_t)b.w;
    *(bf16x8*)(out + i) = t;
  }
}

// ---------------- transpose + convert: in (K x N) fp32 -> out (N x K) bf16 ----------------
__global__ void transpose_cvt(const float* __restrict__ in, bf16_t* __restrict__ out, int K, int N) {
  __shared__ float t[32][33];
  const int bx = blockIdx.x * 32, by = blockIdx.y * 32;
  const int x = threadIdx.x, y = threadIdx.y;
#pragma unroll
  for (int j = 0; j < 32; j += 8) {
    int k = by + y + j, nn = bx + x;
    if (k < K && nn < N) t[y + j][x] = in[(size_t)k * N + nn];
  }
  __syncthreads();
#pragma unroll
  for (int j = 0; j < 32; j += 8) {
    int nn = bx + y + j, k = by + x;
    if (nn < N && k < K) out[(size_t)nn * K + k] = (bf16_t)t[x][y + j];
  }
}

// ---------------- bf16 MFMA GEMM: C[M,N] = A[M,K] @ Bt[N,K]^T ----------------
// A, Bt bf16 row-major; C = fp32 or bf16. 128x128 tile, BK=64, 4 waves.
// XCD-chunked bijective block swizzle (requires nwg%8==0 && gy%8==0, else identity).
template <typename CT>
__global__ __launch_bounds__(256) void gemm_bt(
    const bf16_t* __restrict__ A, const bf16_t* __restrict__ Bt,
    CT* __restrict__ C, int M, int N, int K) {
  __shared__ __align__(16) bf16_t lA[128 * 64];
  __shared__ __align__(16) bf16_t lB[128 * 64];
  const int tid = threadIdx.x;
  const int wave = tid >> 6, lane = tid & 63;

  // ---- block swizzle: chunk per XCD, bx-outer/by-inner inside chunk ----
  const int gx = gridDim.x, gy = gridDim.y;
  const int nwg = gx * gy;
  int bx, by;
  if (((nwg & 7) == 0) && ((gy & 7) == 0)) {
    const int orig = blockIdx.y * gx + blockIdx.x;
    const int wg = (orig & 7) * (nwg >> 3) + (orig >> 3);  // contiguous chunk per XCD
    const int gxB = gx << 3;                                // tiles per 8-row band
    const int band = wg / gxB, rem = wg % gxB;
    bx = rem >> 3;
    by = (band << 3) + (rem & 7);
  } else {
    bx = blockIdx.x; by = blockIdx.y;
  }

  const int row0 = by * 128, col0 = bx * 128;
  const int wr = (wave >> 1) * 64, wc = (wave & 1) * 64;
  f32x4 acc[4][4] = {};
  const int kT = K >> 6;
  const int lr = lane >> 3;          // row within 8-row chunk
  const int lc8 = (lane & 7) * 8;    // col (elements) within 64-wide K slab

  for (int kt = 0; kt < kT; ++kt) {
    const int k0 = kt << 6;
    __syncthreads();  // previous compute done before overwrite
#pragma unroll
    for (int j = 0; j < 4; ++j) {
      const int c = wave * 4 + j;    // chunk 0..15, 8 rows each
      const bf16_t* ga = A + (size_t)(row0 + c * 8 + lr) * K + k0 + lc8;
      gld_lds16(ga, &lA[c * 512]);
      const bf16_t* gb = Bt + (size_t)(col0 + c * 8 + lr) * K + k0 + lc8;
      gld_lds16(gb, &lB[c * 512]);
    }
    __syncthreads();  // staging visible
#pragma unroll
    for (int kk = 0; kk < 2; ++kk) {
      bf16x8 af[4], bfr[4];
      const int kc = kk * 32 + (lane >> 4) * 8;
      const int fr = lane & 15;
#pragma unroll
      for (int m = 0; m < 4; ++m)
        af[m] = *(const bf16x8*)&lA[(wr + m * 16 + fr) * 64 + kc];
#pragma unroll
      for (int n = 0; n < 4; ++n)
        bfr[n] = *(const bf16x8*)&lB[(wc + n * 16 + fr) * 64 + kc];
#pragma unroll
      for (int m = 0; m < 4; ++m)
#pragma unroll
        for (int n = 0; n < 4; ++n)
          acc[m][n] = __builtin_amdgcn_mfma_f32_16x16x32_bf16(af[m], bfr[n], acc[m][n], 0, 0, 0);
    }
  }
  const int fr = lane & 15, fq = lane >> 4;
#pragma unroll
  for (int m = 0; m < 4; ++m)
#pragma unroll
    for (int n = 0; n < 4; ++n) {
      const int col = col0 + wc + n * 16 + fr;
#pragma unroll
      for (int r = 0; r < 4; ++r) {
        const int row = row0 + wr + m * 16 + fq * 4 + r;
        C[(size_t)row * N + col] = (CT)acc[m][n][r];
      }
    }
}

// ---------------- in-place RoPE rotation on 64-wide rope slices ----------------
// one 32-lane group per (token, head); half = 32
__global__ __launch_bounds__(256) void rope_kernel(
    bf16_t* __restrict__ base, int tokStride, int hshift, int posMask) {
  const long idx = (long)blockIdx.x * 8 + (threadIdx.x >> 5);  // tok*heads + h
  const int i = threadIdx.x & 31;
  const long tok = idx >> hshift;
  const int h = (int)(idx & ((1 << hshift) - 1));
  const int pos = (int)(tok & posMask);
  bf16_t* p = base + tok * (long)tokStride + h * 64;
  const float x1 = (float)p[i], x2 = (float)p[i + 32];
  const float invf = expf(-((float)i * (1.0f / 32.f)) * 9.210340371976184f);  // ln(10000)
  float sn, cs;
  sincosf((float)pos * invf, &sn, &cs);
  p[i]      = (bf16_t)(x1 * cs - x2 * sn);
  p[i + 32] = (bf16_t)(x1 * sn + x2 * cs);
}

// ---------------- sparse windowed attention: <=9 keys per query ----------------
// 1 wave per query row; 4 lanes per head (16 heads). fp32 math from bf16 inputs.
// q_comb rows: [q_nope(16*128) | q_rope(16*64)]  stride QCOMB
// kv_comb rows: [k_nope(16*128) | v(16*128) | k_rope(64) | pad]  stride KCOMB
__global__ __launch_bounds__(256) void attn_sparse(
    const bf16_t* __restrict__ qc, const bf16_t* __restrict__ kvc,
    const int* __restrict__ seg, bf16_t* __restrict__ out) {
  const int qrow = blockIdx.x * 4 + (threadIdx.x >> 6);  // b*LQ + qi
  const int lane = threadIdx.x & 63;
  const int h = lane >> 2, sub = lane & 3;
  const int b = qrow >> 12;  // / LQ
  const int s = seg[qrow];
  const int kl = max(0, s - 8);
  const float scale = 0.07216878364870322f;  // 1/sqrt(HD+R)

  float qnf[32], qrf[16];
  {
    const bf16_t* p = qc + (size_t)qrow * QCOMB + h * HD_ + sub * 32;
#pragma unroll
    for (int j = 0; j < 4; ++j) {
      bf16x8 t = *(const bf16x8*)(p + j * 8);
#pragma unroll
      for (int e = 0; e < 8; ++e) qnf[j * 8 + e] = (float)t[e];
    }
    const bf16_t* p2 = qc + (size_t)qrow * QCOMB + 2048 + h * R_ + sub * 16;
#pragma unroll
    for (int j = 0; j < 2; ++j) {
      bf16x8 t = *(const bf16x8*)(p2 + j * 8);
#pragma unroll
      for (int e = 0; e < 8; ++e) qrf[j * 8 + e] = (float)t[e];
    }
  }

  float sc[9];
#pragma unroll
  for (int kk = 0; kk < 9; ++kk) {
    const int kx = kl + kk;
    const bf16_t* kb = kvc + (size_t)(b * LK + kx) * KCOMB;
    float d = 0.f;
    const bf16_t* p = kb + h * HD_ + sub * 32;
#pragma unroll
    for (int j = 0; j < 4; ++j) {
      bf16x8 t = *(const bf16x8*)(p + j * 8);
#pragma unroll
      for (int e = 0; e < 8; ++e) d += qnf[j * 8 + e] * (float)t[e];
    }
    const bf16_t* p2 = kb + 4096 + sub * 16;
#pragma unroll
    for (int j = 0; j < 2; ++j) {
      bf16x8 t = *(const bf16x8*)(p2 + j * 8);
#pragma unroll
      for (int e = 0; e < 8; ++e) d += qrf[j * 8 + e] * (float)t[e];
    }
    d += __shfl_xor(d, 1);
    d += __shfl_xor(d, 2);
    sc[kk] = (kx <= s) ? d * scale : -1e30f;
  }
  float m = sc[0];
#pragma unroll
  for (int kk = 1; kk < 9; ++kk) m = fmaxf(m, sc[kk]);
  float sum = 0.f;
#pragma unroll
  for (int kk = 0; kk < 9; ++kk) { const float p = expf(sc[kk] - m); sc[kk] = p; sum += p; }
  const float inv = 1.f / sum;

  float o[32];
#pragma unroll
  for (int j = 0; j < 32; ++j) o[j] = 0.f;
#pragma unroll
  for (int kk = 0; kk < 9; ++kk) {
    const bf16_t* pv = kvc + (size_t)(b * LK + kl + kk) * KCOMB + 2048 + h * HD_ + sub * 32;
    const float p = sc[kk] * inv;
#pragma unroll
    for (int j = 0; j < 4; ++j) {
      bf16x8 t = *(const bf16x8*)(pv + j * 8);
#pragma unroll
      for (int e = 0; e < 8; ++e) o[j * 8 + e] += p * (float)t[e];
    }
  }
  bf16_t* po = out + (size_t)qrow * (H_ * HD_) + h * HD_ + sub * 32;
#pragma unroll
  for (int j = 0; j < 4; ++j) {
    bf16x8 t;
#pragma unroll
    for (int e = 0; e < 8; ++e) t[e] = (bf16_t)o[j * 8 + e];
    *(bf16x8*)(po + j * 8) = t;
  }
}

extern "C" void kernel_launch(void* const* d_in, const int* in_sizes, int n_in,
                              void* d_out, int out_size, void* d_ws, size_t ws_size,
                              hipStream_t stream) {
  const float* q     = (const float*)d_in[0];
  const float* kv    = (const float*)d_in[1];
  const int*   seg   = (const int*)d_in[2];
  const float* W_kvc = (const float*)d_in[3];
  const float* W_dq  = (const float*)d_in[4];
  const float* W_uq  = (const float*)d_in[5];
  const float* W_qr  = (const float*)d_in[6];
  const float* W_uk  = (const float*)d_in[7];
  const float* W_kr  = (const float*)d_in[8];
  const float* W_uv  = (const float*)d_in[9];
  const float* W_o   = (const float*)d_in[10];
  float* out = (float*)d_out;
  (void)in_sizes; (void)n_in; (void)out_size; (void)ws_size;

  char* ws = (char*)d_ws;
  size_t off = 0;
  auto alloc = [&](size_t bytes) {
    char* p = ws + off;
    off = (off + bytes + 255) & ~(size_t)255;
    return p;
  };
  bf16_t* q_bf    = (bf16_t*)alloc((size_t)B_ * LQ * QDIM * 2);   // reused as attn_o
  bf16_t* kv_bf   = (bf16_t*)alloc((size_t)B_ * LK * KVDIM * 2);
  bf16_t* WkvcT   = (bf16_t*)alloc((size_t)KVC_ * KVDIM * 2);
  bf16_t* WdqT    = (bf16_t*)alloc((size_t)QC_ * QDIM * 2);
  bf16_t* WuqrT   = (bf16_t*)alloc((size_t)QCOMB * QC_ * 2);      // [W_uq^T ; W_qr^T]
  bf16_t* WkvT    = (bf16_t*)alloc((size_t)KCOMB * KVC_ * 2);     // [W_uk^T ; W_uv^T ; W_kr^T ; pad]
  bf16_t* WoT     = (bf16_t*)alloc((size_t)QDIM * (H_ * HD_) * 2);
  bf16_t* kv_c    = (bf16_t*)alloc((size_t)B_ * LK * KVC_ * 2);
  bf16_t* q_c     = (bf16_t*)alloc((size_t)B_ * LQ * QC_ * 2);
  bf16_t* q_comb  = (bf16_t*)alloc((size_t)B_ * LQ * QCOMB * 2);
  bf16_t* kv_comb = (bf16_t*)alloc((size_t)B_ * LK * KCOMB * 2);
  bf16_t* attn_o  = q_bf;  // q_bf dead after q_c GEMM

  // ---- convert inputs to bf16 ----
  cvt_f32_bf16<<<4096, 256, 0, stream>>>(q, q_bf, (long)B_ * LQ * QDIM);
  cvt_f32_bf16<<<2048, 256, 0, stream>>>(kv, kv_bf, (long)B_ * LK * KVDIM);
  const dim3 tb(32, 8);
  transpose_cvt<<<dim3(KVC_ / 32, KVDIM / 32), tb, 0, stream>>>(W_kvc, WkvcT, KVDIM, KVC_);
  transpose_cvt<<<dim3(QC_ / 32, QDIM / 32), tb, 0, stream>>>(W_dq, WdqT, QDIM, QC_);
  // fused q-up weights: rows 0..2047 = W_uq^T, rows 2048..3071 = W_qr^T
  transpose_cvt<<<dim3((H_ * HD_) / 32, QC_ / 32), tb, 0, stream>>>(W_uq, WuqrT, QC_, H_ * HD_);
  transpose_cvt<<<dim3((H_ * R_) / 32, QC_ / 32), tb, 0, stream>>>(
      W_qr, WuqrT + (size_t)(H_ * HD_) * QC_, QC_, H_ * R_);
  // fused kv-up weights: rows 0..2047 = W_uk^T, 2048..4095 = W_uv^T, 4096..4159 = W_kr^T, rest unused
  transpose_cvt<<<dim3((H_ * HD_) / 32, KVC_ / 32), tb, 0, stream>>>(W_uk, WkvT, KVC_, H_ * HD_);
  transpose_cvt<<<dim3((H_ * HD_) / 32, KVC_ / 32), tb, 0, stream>>>(
      W_uv, WkvT + (size_t)(H_ * HD_) * KVC_, KVC_, H_ * HD_);
  transpose_cvt<<<dim3(R_ / 32, KVC_ / 32), tb, 0, stream>>>(
      W_kr, WkvT + (size_t)2 * (H_ * HD_) * KVC_, KVC_, R_);
  transpose_cvt<<<dim3(QDIM / 32, (H_ * HD_) / 32), tb, 0, stream>>>(W_o, WoT, H_ * HD_, QDIM);

  // ---- projection GEMMs (C = A @ Bt^T) ----
  gemm_bt<bf16_t><<<dim3(KVC_ / 128, (B_ * LK) / 128), 256, 0, stream>>>(
      kv_bf, WkvcT, kv_c, B_ * LK, KVC_, KVDIM);
  gemm_bt<bf16_t><<<dim3(QC_ / 128, (B_ * LQ) / 128), 256, 0, stream>>>(
      q_bf, WdqT, q_c, B_ * LQ, QC_, QDIM);
  gemm_bt<bf16_t><<<dim3(QCOMB / 128, (B_ * LQ) / 128), 256, 0, stream>>>(
      q_c, WuqrT, q_comb, B_ * LQ, QCOMB, QC_);
  rope_kernel<<<(B_ * LQ * H_) / 8, 256, 0, stream>>>(q_comb + 2048, QCOMB, 4, LQ - 1);
  gemm_bt<bf16_t><<<dim3(KCOMB / 128, (B_ * LK) / 128), 256, 0, stream>>>(
      kv_c, WkvT, kv_comb, B_ * LK, KCOMB, KVC_);
  rope_kernel<<<(B_ * LK) / 8, 256, 0, stream>>>(kv_comb + 4096, KCOMB, 0, LK - 1);

  // ---- sparse attention (<=9 keys/query) ----
  attn_sparse<<<(B_ * LQ) / 4, 256, 0, stream>>>(q_comb, kv_comb, seg, attn_o);

  // ---- output projection ----
  gemm_bt<float><<<dim3(QDIM / 128, (B_ * LQ) / 128), 256, 0, stream>>>(
      attn_o, WoT, out, B_ * LQ, QDIM, H_ * HD_);
}

// Round 3
// 397.633 us; speedup vs baseline: 1.0651x; 1.0245x over previous
//
#include <hip/hip_runtime.h>
#include <math.h>

typedef __bf16 bf16_t;
typedef __bf16 bf16x8 __attribute__((ext_vector_type(8)));
typedef float f32x4 __attribute__((ext_vector_type(4)));

#define B_    2
#define LQ    4096
#define LK    1024
#define QDIM  2048
#define KVDIM 2048
#define H_    16
#define HD_   128
#define KVC_  512
#define QC_   768
#define R_    64

// fused row widths
#define QCOMB 3072   // [q_nope(2048) | q_rope(1024)]
#define KCOMB 4224   // [k_nope(2048) | v(2048) | k_rope(64) | pad(64)]

typedef __attribute__((address_space(1))) void gvoid_t;
typedef __attribute__((address_space(3))) void lvoid_t;

static __device__ __forceinline__ void gld_lds16(const void* g, void* l) {
  __builtin_amdgcn_global_load_lds((gvoid_t*)(void*)g, (lvoid_t*)l, 16, 0, 0);
}

// ---------------- fp32 -> bf16 convert (vectorized) ----------------
__global__ void cvt_f32_bf16(const float* __restrict__ in, bf16_t* __restrict__ out, long n) {
  long i = ((long)blockIdx.x * blockDim.x + threadIdx.x) * 8;
  const long stride = (long)gridDim.x * blockDim.x * 8;
  for (; i < n; i += stride) {
    float4 a = *(const float4*)(in + i);
    float4 b = *(const float4*)(in + i + 4);
    bf16x8 t;
    t[0] = (bf16_t)a.x; t[1] = (bf16_t)a.y; t[2] = (bf16_t)a.z; t[3] = (bf16_t)a.w;
    t[4] = (bf16_t)b.x; t[5] = (bf16_t)b.y; t[6] = (bf16_t)b.z; t[7] = (bf16_t)b.w;
    *(bf16x8*)(out + i) = t;
  }
}

// ---------------- transpose + convert: in (K x N) fp32 -> out (N x K) bf16 ----------------
__global__ void transpose_cvt(const float* __restrict__ in, bf16_t* __restrict__ out, int K, int N) {
  __shared__ float t[32][33];
  const int bx = blockIdx.x * 32, by = blockIdx.y * 32;
  const int x = threadIdx.x, y = threadIdx.y;
#pragma unroll
  for (int j = 0; j < 32; j += 8) {
    int k = by + y + j, nn = bx + x;
    if (k < K && nn < N) t[y + j][x] = in[(size_t)k * N + nn];
  }
  __syncthreads();
#pragma unroll
  for (int j = 0; j < 32; j += 8) {
    int nn = bx + y + j, k = by + x;
    if (nn < N && k < K) out[(size_t)nn * K + k] = (bf16_t)t[x][y + j];
  }
}

// ---------------- small-M bf16 MFMA GEMM (128x128, BK=64, 4 waves) ----------------
template <typename CT>
__global__ __launch_bounds__(256) void gemm_bt(
    const bf16_t* __restrict__ A, const bf16_t* __restrict__ Bt,
    CT* __restrict__ C, int M, int N, int K) {
  __shared__ __align__(16) bf16_t lA[128 * 64];
  __shared__ __align__(16) bf16_t lB[128 * 64];
  const int tid = threadIdx.x;
  const int wave = tid >> 6, lane = tid & 63;

  const int gx = gridDim.x, gy = gridDim.y;
  const int nwg = gx * gy;
  int bx, by;
  if (((nwg & 7) == 0) && ((gy & 7) == 0)) {
    const int orig = blockIdx.y * gx + blockIdx.x;
    const int wg = (orig & 7) * (nwg >> 3) + (orig >> 3);
    const int gxB = gx << 3;
    const int band = wg / gxB, rem = wg % gxB;
    bx = rem >> 3;
    by = (band << 3) + (rem & 7);
  } else {
    bx = blockIdx.x; by = blockIdx.y;
  }

  const int row0 = by * 128, col0 = bx * 128;
  const int wr = (wave >> 1) * 64, wc = (wave & 1) * 64;
  f32x4 acc[4][4] = {};
  const int kT = K >> 6;
  const int lr = lane >> 3;
  const int lc8 = (lane & 7) * 8;

  for (int kt = 0; kt < kT; ++kt) {
    const int k0 = kt << 6;
    __syncthreads();
#pragma unroll
    for (int j = 0; j < 4; ++j) {
      const int c = wave * 4 + j;
      const bf16_t* ga = A + (size_t)(row0 + c * 8 + lr) * K + k0 + lc8;
      gld_lds16(ga, &lA[c * 512]);
      const bf16_t* gb = Bt + (size_t)(col0 + c * 8 + lr) * K + k0 + lc8;
      gld_lds16(gb, &lB[c * 512]);
    }
    __syncthreads();
#pragma unroll
    for (int kk = 0; kk < 2; ++kk) {
      bf16x8 af[4], bfr[4];
      const int kc = kk * 32 + (lane >> 4) * 8;
      const int fr = lane & 15;
#pragma unroll
      for (int m = 0; m < 4; ++m)
        af[m] = *(const bf16x8*)&lA[(wr + m * 16 + fr) * 64 + kc];
#pragma unroll
      for (int n = 0; n < 4; ++n)
        bfr[n] = *(const bf16x8*)&lB[(wc + n * 16 + fr) * 64 + kc];
#pragma unroll
      for (int m = 0; m < 4; ++m)
#pragma unroll
        for (int n = 0; n < 4; ++n)
          acc[m][n] = __builtin_amdgcn_mfma_f32_16x16x32_bf16(af[m], bfr[n], acc[m][n], 0, 0, 0);
    }
  }
  const int fr = lane & 15, fq = lane >> 4;
#pragma unroll
  for (int m = 0; m < 4; ++m)
#pragma unroll
    for (int n = 0; n < 4; ++n) {
      const int col = col0 + wc + n * 16 + fr;
#pragma unroll
      for (int r = 0; r < 4; ++r) {
        const int row = row0 + wr + m * 16 + fq * 4 + r;
        C[(size_t)row * N + col] = (CT)acc[m][n][r];
      }
    }
}

// ---------------- big-M pipelined GEMM: BM=256, BN=128, BK=64, 8 waves ----------------
// 3 LDS buffers (144 KiB), prefetch distance 2, counted vmcnt (never 0 in loop),
// raw s_barrier (no drain), LDS XOR swizzle via pre-swizzled global source.
// Requires: M%256==0, N%128==0, K%64==0, K/64>=3, gridDim=(N/128, M/256).
template <typename CT>
__global__ __launch_bounds__(512, 2) void gemm_big(
    const bf16_t* __restrict__ A, const bf16_t* __restrict__ Bt,
    CT* __restrict__ C, int M, int N, int K) {
  __shared__ __align__(16) bf16_t lA[3][256 * 64];
  __shared__ __align__(16) bf16_t lB[3][128 * 64];
  const int tid = threadIdx.x;
  const int w = tid >> 6, lane = tid & 63;

  const int gx = gridDim.x, gy = gridDim.y;
  const int nwg = gx * gy;
  int bx, by;
  {
    const int orig = blockIdx.y * gx + blockIdx.x;
    const int wg = (orig & 7) * (nwg >> 3) + (orig >> 3);  // per-XCD contiguous chunk
    const int gxB = gx << 3;
    const int band = wg / gxB, rem = wg % gxB;
    bx = rem >> 3;
    by = (band << 3) + (rem & 7);
  }
  const int row0 = by * 256, col0 = bx * 128;
  const int wm = w >> 2, wn = w & 3;
  const int lr = lane >> 3;                 // 0..7: row within 8-row segment
  const int kswz = ((lane & 7) ^ lr) * 8;   // pre-swizzled global k-offset (elements)
  const int nt = K >> 6;

  // stage K-tile t into buffer buf: A 4 segs/wave, B 2 segs/wave, 1 KiB each
  auto STAGE = [&](int t, int buf) {
    const int k0 = t << 6;
#pragma unroll
    for (int j = 0; j < 4; ++j) {
      const int s = j * 8 + w;              // segment 0..31 = rows s*8..s*8+7
      gld_lds16(A + (size_t)(row0 + s * 8 + lr) * K + k0 + kswz, &lA[buf][s * 512]);
    }
#pragma unroll
    for (int j = 0; j < 2; ++j) {
      const int s = j * 8 + w;              // segment 0..15
      gld_lds16(Bt + (size_t)(col0 + s * 8 + lr) * K + k0 + kswz, &lB[buf][s * 512]);
    }
  };

  f32x4 acc[8][2] = {};
  const int fr = lane & 15, fq = lane >> 4;

  // compute one K-tile from buffer buf; ends with read-complete guard + barrier
  auto BODY = [&](int buf) {
    asm volatile("" ::: "memory");
#pragma unroll
    for (int kk = 0; kk < 2; ++kk) {
      const int swzk = (kk * 32 + fq * 8) ^ ((fr & 7) << 3);  // swizzled read col
      bf16x8 af[8], bfr[2];
#pragma unroll
      for (int nf = 0; nf < 2; ++nf)
        bfr[nf] = *(const bf16x8*)&lB[buf][(wn * 32 + nf * 16 + fr) * 64 + swzk];
#pragma unroll
      for (int mf = 0; mf < 8; ++mf)
        af[mf] = *(const bf16x8*)&lA[buf][(wm * 128 + mf * 16 + fr) * 64 + swzk];
      __builtin_amdgcn_s_setprio(1);
#pragma unroll
      for (int mf = 0; mf < 8; ++mf)
#pragma unroll
        for (int nf = 0; nf < 2; ++nf)
          acc[mf][nf] = __builtin_amdgcn_mfma_f32_16x16x32_bf16(af[mf], bfr[nf], acc[mf][nf], 0, 0, 0);
      __builtin_amdgcn_s_setprio(0);
    }
    // all ds_reads of this buffer complete before next iter's STAGE may overwrite it
    asm volatile("s_waitcnt lgkmcnt(0)" ::: "memory");
    __builtin_amdgcn_sched_barrier(0);
    __builtin_amdgcn_s_barrier();  // B2
  };

  STAGE(0, 0);
  STAGE(1, 1);
  int bs = 2, bt = 0;
  for (int t = 0; t + 2 < nt; ++t) {
    STAGE(t + 2, bs);                                   // 6 loads -> outstanding <= 18
    asm volatile("s_waitcnt vmcnt(12)" ::: "memory");   // tile t landed; t+1,t+2 in flight
    __builtin_amdgcn_s_barrier();                       // B1: all waves' tile-t loads landed
    BODY(bt);
    bs = (bs == 2) ? 0 : bs + 1;
    bt = (bt == 2) ? 0 : bt + 1;
  }
  asm volatile("s_waitcnt vmcnt(6)" ::: "memory");      // tile nt-2 landed
  __builtin_amdgcn_s_barrier();
  BODY(bt);
  bt = (bt == 2) ? 0 : bt + 1;
  asm volatile("s_waitcnt vmcnt(0)" ::: "memory");      // tile nt-1 landed
  __builtin_amdgcn_s_barrier();
  BODY(bt);

  // epilogue: C[row][col], 16x16x32 C-layout col=lane&15, row=(lane>>4)*4+r
#pragma unroll
  for (int mf = 0; mf < 8; ++mf)
#pragma unroll
    for (int nf = 0; nf < 2; ++nf) {
      const int col = col0 + wn * 32 + nf * 16 + fr;
#pragma unroll
      for (int r = 0; r < 4; ++r) {
        const int row = row0 + wm * 128 + mf * 16 + fq * 4 + r;
        C[(size_t)row * N + col] = (CT)acc[mf][nf][r];
      }
    }
}

// ---------------- in-place RoPE rotation on 64-wide rope slices ----------------
__global__ __launch_bounds__(256) void rope_kernel(
    bf16_t* __restrict__ base, int tokStride, int hshift, int posMask) {
  const long idx = (long)blockIdx.x * 8 + (threadIdx.x >> 5);  // tok*heads + h
  const int i = threadIdx.x & 31;
  const long tok = idx >> hshift;
  const int h = (int)(idx & ((1 << hshift) - 1));
  const int pos = (int)(tok & posMask);
  bf16_t* p = base + tok * (long)tokStride + h * 64;
  const float x1 = (float)p[i], x2 = (float)p[i + 32];
  const float invf = expf(-((float)i * (1.0f / 32.f)) * 9.210340371976184f);  // ln(10000)
  float sn, cs;
  sincosf((float)pos * invf, &sn, &cs);
  p[i]      = (bf16_t)(x1 * cs - x2 * sn);
  p[i + 32] = (bf16_t)(x1 * sn + x2 * cs);
}

// ---------------- sparse windowed attention: <=9 keys per query ----------------
__global__ __launch_bounds__(256) void attn_sparse(
    const bf16_t* __restrict__ qc, const bf16_t* __restrict__ kvc,
    const int* __restrict__ seg, bf16_t* __restrict__ out) {
  const int qrow = blockIdx.x * 4 + (threadIdx.x >> 6);  // b*LQ + qi
  const int lane = threadIdx.x & 63;
  const int h = lane >> 2, sub = lane & 3;
  const int b = qrow >> 12;  // / LQ
  const int s = seg[qrow];
  const int kl = max(0, s - 8);
  const float scale = 0.07216878364870322f;  // 1/sqrt(HD+R)

  float qnf[32], qrf[16];
  {
    const bf16_t* p = qc + (size_t)qrow * QCOMB + h * HD_ + sub * 32;
#pragma unroll
    for (int j = 0; j < 4; ++j) {
      bf16x8 t = *(const bf16x8*)(p + j * 8);
#pragma unroll
      for (int e = 0; e < 8; ++e) qnf[j * 8 + e] = (float)t[e];
    }
    const bf16_t* p2 = qc + (size_t)qrow * QCOMB + 2048 + h * R_ + sub * 16;
#pragma unroll
    for (int j = 0; j < 2; ++j) {
      bf16x8 t = *(const bf16x8*)(p2 + j * 8);
#pragma unroll
      for (int e = 0; e < 8; ++e) qrf[j * 8 + e] = (float)t[e];
    }
  }

  float sc[9];
#pragma unroll
  for (int kk = 0; kk < 9; ++kk) {
    const int kx = kl + kk;
    const bf16_t* kb = kvc + (size_t)(b * LK + kx) * KCOMB;
    float d = 0.f;
    const bf16_t* p = kb + h * HD_ + sub * 32;
#pragma unroll
    for (int j = 0; j < 4; ++j) {
      bf16x8 t = *(const bf16x8*)(p + j * 8);
#pragma unroll
      for (int e = 0; e < 8; ++e) d += qnf[j * 8 + e] * (float)t[e];
    }
    const bf16_t* p2 = kb + 4096 + sub * 16;
#pragma unroll
    for (int j = 0; j < 2; ++j) {
      bf16x8 t = *(const bf16x8*)(p2 + j * 8);
#pragma unroll
      for (int e = 0; e < 8; ++e) d += qrf[j * 8 + e] * (float)t[e];
    }
    d += __shfl_xor(d, 1);
    d += __shfl_xor(d, 2);
    sc[kk] = (kx <= s) ? d * scale : -1e30f;
  }
  float m = sc[0];
#pragma unroll
  for (int kk = 1; kk < 9; ++kk) m = fmaxf(m, sc[kk]);
  float sum = 0.f;
#pragma unroll
  for (int kk = 0; kk < 9; ++kk) { const float p = expf(sc[kk] - m); sc[kk] = p; sum += p; }
  const float inv = 1.f / sum;

  float o[32];
#pragma unroll
  for (int j = 0; j < 32; ++j) o[j] = 0.f;
#pragma unroll
  for (int kk = 0; kk < 9; ++kk) {
    const bf16_t* pv = kvc + (size_t)(b * LK + kl + kk) * KCOMB + 2048 + h * HD_ + sub * 32;
    const float p = sc[kk] * inv;
#pragma unroll
    for (int j = 0; j < 4; ++j) {
      bf16x8 t = *(const bf16x8*)(pv + j * 8);
#pragma unroll
      for (int e = 0; e < 8; ++e) o[j * 8 + e] += p * (float)t[e];
    }
  }
  bf16_t* po = out + (size_t)qrow * (H_ * HD_) + h * HD_ + sub * 32;
#pragma unroll
  for (int j = 0; j < 4; ++j) {
    bf16x8 t;
#pragma unroll
    for (int e = 0; e < 8; ++e) t[e] = (bf16_t)o[j * 8 + e];
    *(bf16x8*)(po + j * 8) = t;
  }
}

extern "C" void kernel_launch(void* const* d_in, const int* in_sizes, int n_in,
                              void* d_out, int out_size, void* d_ws, size_t ws_size,
                              hipStream_t stream) {
  const float* q     = (const float*)d_in[0];
  const float* kv    = (const float*)d_in[1];
  const int*   seg   = (const int*)d_in[2];
  const float* W_kvc = (const float*)d_in[3];
  const float* W_dq  = (const float*)d_in[4];
  const float* W_uq  = (const float*)d_in[5];
  const float* W_qr  = (const float*)d_in[6];
  const float* W_uk  = (const float*)d_in[7];
  const float* W_kr  = (const float*)d_in[8];
  const float* W_uv  = (const float*)d_in[9];
  const float* W_o   = (const float*)d_in[10];
  float* out = (float*)d_out;
  (void)in_sizes; (void)n_in; (void)out_size; (void)ws_size;

  char* ws = (char*)d_ws;
  size_t off = 0;
  auto alloc = [&](size_t bytes) {
    char* p = ws + off;
    off = (off + bytes + 255) & ~(size_t)255;
    return p;
  };
  bf16_t* q_bf    = (bf16_t*)alloc((size_t)B_ * LQ * QDIM * 2);   // reused as attn_o
  bf16_t* kv_bf   = (bf16_t*)alloc((size_t)B_ * LK * KVDIM * 2);
  bf16_t* WkvcT   = (bf16_t*)alloc((size_t)KVC_ * KVDIM * 2);
  bf16_t* WdqT    = (bf16_t*)alloc((size_t)QC_ * QDIM * 2);
  bf16_t* WuqrT   = (bf16_t*)alloc((size_t)QCOMB * QC_ * 2);      // [W_uq^T ; W_qr^T]
  bf16_t* WkvT    = (bf16_t*)alloc((size_t)KCOMB * KVC_ * 2);     // [W_uk^T ; W_uv^T ; W_kr^T ; pad]
  bf16_t* WoT     = (bf16_t*)alloc((size_t)QDIM * (H_ * HD_) * 2);
  bf16_t* kv_c    = (bf16_t*)alloc((size_t)B_ * LK * KVC_ * 2);
  bf16_t* q_c     = (bf16_t*)alloc((size_t)B_ * LQ * QC_ * 2);
  bf16_t* q_comb  = (bf16_t*)alloc((size_t)B_ * LQ * QCOMB * 2);
  bf16_t* kv_comb = (bf16_t*)alloc((size_t)B_ * LK * KCOMB * 2);
  bf16_t* attn_o  = q_bf;  // q_bf dead after q_c GEMM

  // ---- convert inputs to bf16 ----
  cvt_f32_bf16<<<4096, 256, 0, stream>>>(q, q_bf, (long)B_ * LQ * QDIM);
  cvt_f32_bf16<<<2048, 256, 0, stream>>>(kv, kv_bf, (long)B_ * LK * KVDIM);
  const dim3 tb(32, 8);
  transpose_cvt<<<dim3(KVC_ / 32, KVDIM / 32), tb, 0, stream>>>(W_kvc, WkvcT, KVDIM, KVC_);
  transpose_cvt<<<dim3(QC_ / 32, QDIM / 32), tb, 0, stream>>>(W_dq, WdqT, QDIM, QC_);
  transpose_cvt<<<dim3((H_ * HD_) / 32, QC_ / 32), tb, 0, stream>>>(W_uq, WuqrT, QC_, H_ * HD_);
  transpose_cvt<<<dim3((H_ * R_) / 32, QC_ / 32), tb, 0, stream>>>(
      W_qr, WuqrT + (size_t)(H_ * HD_) * QC_, QC_, H_ * R_);
  transpose_cvt<<<dim3((H_ * HD_) / 32, KVC_ / 32), tb, 0, stream>>>(W_uk, WkvT, KVC_, H_ * HD_);
  transpose_cvt<<<dim3((H_ * HD_) / 32, KVC_ / 32), tb, 0, stream>>>(
      W_uv, WkvT + (size_t)(H_ * HD_) * KVC_, KVC_, H_ * HD_);
  transpose_cvt<<<dim3(R_ / 32, KVC_ / 32), tb, 0, stream>>>(
      W_kr, WkvT + (size_t)2 * (H_ * HD_) * KVC_, KVC_, R_);
  transpose_cvt<<<dim3(QDIM / 32, (H_ * HD_) / 32), tb, 0, stream>>>(W_o, WoT, H_ * HD_, QDIM);

  // ---- projection GEMMs (C = A @ Bt^T) ----
  gemm_bt<bf16_t><<<dim3(KVC_ / 128, (B_ * LK) / 128), 256, 0, stream>>>(
      kv_bf, WkvcT, kv_c, B_ * LK, KVC_, KVDIM);
  gemm_big<bf16_t><<<dim3(QC_ / 128, (B_ * LQ) / 256), 512, 0, stream>>>(
      q_bf, WdqT, q_c, B_ * LQ, QC_, QDIM);
  gemm_big<bf16_t><<<dim3(QCOMB / 128, (B_ * LQ) / 256), 512, 0, stream>>>(
      q_c, WuqrT, q_comb, B_ * LQ, QCOMB, QC_);
  rope_kernel<<<(B_ * LQ * H_) / 8, 256, 0, stream>>>(q_comb + 2048, QCOMB, 4, LQ - 1);
  gemm_bt<bf16_t><<<dim3(KCOMB / 128, (B_ * LK) / 128), 256, 0, stream>>>(
      kv_c, WkvT, kv_comb, B_ * LK, KCOMB, KVC_);
  rope_kernel<<<(B_ * LK) / 8, 256, 0, stream>>>(kv_comb + 4096, KCOMB, 0, LK - 1);

  // ---- sparse attention (<=9 keys/query) ----
  attn_sparse<<<(B_ * LQ) / 4, 256, 0, stream>>>(q_comb, kv_comb, seg, attn_o);

  // ---- output projection ----
  gemm_big<float><<<dim3(QDIM / 128, (B_ * LQ) / 256), 512, 0, stream>>>(
      attn_o, WoT, out, B_ * LQ, QDIM, H_ * HD_);
}

// Round 4
// 378.436 us; speedup vs baseline: 1.1191x; 1.0507x over previous
//
#include <hip/hip_runtime.h>
#include <math.h>

typedef __bf16 bf16_t;
typedef __bf16 bf16x8 __attribute__((ext_vector_type(8)));
typedef float f32x4 __attribute__((ext_vector_type(4)));

#define B_    2
#define LQ    4096
#define LK    1024
#define QDIM  2048
#define KVDIM 2048
#define H_    16
#define HD_   128
#define KVC_  512
#define QC_   768
#define R_    64

// fused row widths
#define QCOMB 3072   // [q_nope(2048) | q_rope(1024)]
#define KCOMB 4224   // [k_nope(2048) | v(2048) | k_rope(64) | pad(64)]

typedef __attribute__((address_space(1))) void gvoid_t;
typedef __attribute__((address_space(3))) void lvoid_t;

static __device__ __forceinline__ void gld_lds16(const void* g, void* l) {
  __builtin_amdgcn_global_load_lds((gvoid_t*)(void*)g, (lvoid_t*)l, 16, 0, 0);
}

// ---------------- fp32 -> bf16 convert (vectorized) ----------------
__global__ void cvt_f32_bf16(const float* __restrict__ in, bf16_t* __restrict__ out, long n) {
  long i = ((long)blockIdx.x * blockDim.x + threadIdx.x) * 8;
  const long stride = (long)gridDim.x * blockDim.x * 8;
  for (; i < n; i += stride) {
    float4 a = *(const float4*)(in + i);
    float4 b = *(const float4*)(in + i + 4);
    bf16x8 t;
    t[0] = (bf16_t)a.x; t[1] = (bf16_t)a.y; t[2] = (bf16_t)a.z; t[3] = (bf16_t)a.w;
    t[4] = (bf16_t)b.x; t[5] = (bf16_t)b.y; t[6] = (bf16_t)b.z; t[7] = (bf16_t)b.w;
    *(bf16x8*)(out + i) = t;
  }
}

// ---------------- transpose + convert: in (K x N) fp32 -> out (N x K) bf16 ----------------
__global__ void transpose_cvt(const float* __restrict__ in, bf16_t* __restrict__ out, int K, int N) {
  __shared__ float t[32][33];
  const int bx = blockIdx.x * 32, by = blockIdx.y * 32;
  const int x = threadIdx.x, y = threadIdx.y;
#pragma unroll
  for (int j = 0; j < 32; j += 8) {
    int k = by + y + j, nn = bx + x;
    if (k < K && nn < N) t[y + j][x] = in[(size_t)k * N + nn];
  }
  __syncthreads();
#pragma unroll
  for (int j = 0; j < 32; j += 8) {
    int nn = bx + y + j, k = by + x;
    if (nn < N && k < K) out[(size_t)nn * K + k] = (bf16_t)t[x][y + j];
  }
}

// ---------------- small-M bf16 MFMA GEMM (128x128, BK=64, 4 waves) ----------------
template <typename CT>
__global__ __launch_bounds__(256) void gemm_bt(
    const bf16_t* __restrict__ A, const bf16_t* __restrict__ Bt,
    CT* __restrict__ C, int M, int N, int K) {
  __shared__ __align__(16) bf16_t lA[128 * 64];
  __shared__ __align__(16) bf16_t lB[128 * 64];
  const int tid = threadIdx.x;
  const int wave = tid >> 6, lane = tid & 63;

  const int gx = gridDim.x, gy = gridDim.y;
  const int nwg = gx * gy;
  int bx, by;
  if (((nwg & 7) == 0) && ((gy & 7) == 0)) {
    const int orig = blockIdx.y * gx + blockIdx.x;
    const int wg = (orig & 7) * (nwg >> 3) + (orig >> 3);
    const int gxB = gx << 3;
    const int band = wg / gxB, rem = wg % gxB;
    bx = rem >> 3;
    by = (band << 3) + (rem & 7);
  } else {
    bx = blockIdx.x; by = blockIdx.y;
  }

  const int row0 = by * 128, col0 = bx * 128;
  const int wr = (wave >> 1) * 64, wc = (wave & 1) * 64;
  f32x4 acc[4][4] = {};
  const int kT = K >> 6;
  const int lr = lane >> 3;
  const int lc8 = (lane & 7) * 8;

  for (int kt = 0; kt < kT; ++kt) {
    const int k0 = kt << 6;
    __syncthreads();
#pragma unroll
    for (int j = 0; j < 4; ++j) {
      const int c = wave * 4 + j;
      const bf16_t* ga = A + (size_t)(row0 + c * 8 + lr) * K + k0 + lc8;
      gld_lds16(ga, &lA[c * 512]);
      const bf16_t* gb = Bt + (size_t)(col0 + c * 8 + lr) * K + k0 + lc8;
      gld_lds16(gb, &lB[c * 512]);
    }
    __syncthreads();
#pragma unroll
    for (int kk = 0; kk < 2; ++kk) {
      bf16x8 af[4], bfr[4];
      const int kc = kk * 32 + (lane >> 4) * 8;
      const int fr = lane & 15;
#pragma unroll
      for (int m = 0; m < 4; ++m)
        af[m] = *(const bf16x8*)&lA[(wr + m * 16 + fr) * 64 + kc];
#pragma unroll
      for (int n = 0; n < 4; ++n)
        bfr[n] = *(const bf16x8*)&lB[(wc + n * 16 + fr) * 64 + kc];
#pragma unroll
      for (int m = 0; m < 4; ++m)
#pragma unroll
        for (int n = 0; n < 4; ++n)
          acc[m][n] = __builtin_amdgcn_mfma_f32_16x16x32_bf16(af[m], bfr[n], acc[m][n], 0, 0, 0);
    }
  }
  const int fr = lane & 15, fq = lane >> 4;
#pragma unroll
  for (int m = 0; m < 4; ++m)
#pragma unroll
    for (int n = 0; n < 4; ++n) {
      const int col = col0 + wc + n * 16 + fr;
#pragma unroll
      for (int r = 0; r < 4; ++r) {
        const int row = row0 + wr + m * 16 + fq * 4 + r;
        C[(size_t)row * N + col] = (CT)acc[m][n][r];
      }
    }
}

// ---------------- big pipelined GEMM v2: BM=256, BN=TN, BK=64, 8 waves (2Mx4N) ----------------
// 2 LDS buffers, counted vmcnt (never 0 mid-loop), register k-step double-buffering
// (read next k-step's fragments under current MFMA cluster), LDS XOR swizzle via
// pre-swizzled global source. Requires M%256==0, N%TN==0, K%64==0, K/64>=2.
template <int TN, typename CT>
__global__ __launch_bounds__(512, 2) void gemm_big2(
    const bf16_t* __restrict__ A, const bf16_t* __restrict__ Bt,
    CT* __restrict__ C, int M, int N, int K) {
  constexpr int NF = TN / 64;          // n-frags per wave (wave n-tile = TN/4)
  constexpr int LW = 4 + TN / 64;      // gld_lds per wave per K-tile
  __shared__ __align__(16) bf16_t lA[2][256 * 64];
  __shared__ __align__(16) bf16_t lB[2][TN * 64];
  const int tid = threadIdx.x;
  const int w = tid >> 6, lane = tid & 63;

  // XCD swizzle: contiguous by-chunk per XCD, bx inner (nwg%8==0 for all our grids)
  const int gx = gridDim.x;
  const int nwg = gx * gridDim.y;
  const int orig = blockIdx.y * gx + blockIdx.x;
  const int wg = (orig & 7) * (nwg >> 3) + (orig >> 3);
  const int bx = wg % gx, by = wg / gx;

  const int row0 = by * 256, col0 = bx * TN;
  const int wm = w >> 2, wn = w & 3;
  const int lr = lane >> 3;
  const int kswz = ((lane & 7) ^ lr) * 8;   // pre-swizzled global k-offset
  const int nt = K >> 6;
  const int fr = lane & 15, fq = lane >> 4;

  auto STAGE = [&](int t, int buf) {
    const int k0 = t << 6;
#pragma unroll
    for (int j = 0; j < 4; ++j) {
      const int s = j * 8 + w;
      gld_lds16(A + (size_t)(row0 + s * 8 + lr) * K + k0 + kswz, &lA[buf][s * 512]);
    }
#pragma unroll
    for (int j = 0; j < TN / 64; ++j) {
      const int s = j * 8 + w;
      gld_lds16(Bt + (size_t)(col0 + s * 8 + lr) * K + k0 + kswz, &lB[buf][s * 512]);
    }
  };

  bf16x8 aA[8], bA[NF], aB[8], bB[NF];
  f32x4 acc[8][NF];
#pragma unroll
  for (int i = 0; i < 8; ++i)
#pragma unroll
    for (int j = 0; j < NF; ++j) acc[i][j] = f32x4{0.f, 0.f, 0.f, 0.f};

  auto READ = [&](int buf, int kk, bf16x8* a, bf16x8* b) {
    const int swzk = (kk * 32 + fq * 8) ^ ((fr & 7) << 3);
#pragma unroll
    for (int mf = 0; mf < 8; ++mf)
      a[mf] = *(const bf16x8*)&lA[buf][(wm * 128 + mf * 16 + fr) * 64 + swzk];
#pragma unroll
    for (int nf = 0; nf < NF; ++nf)
      b[nf] = *(const bf16x8*)&lB[buf][(wn * (TN / 4) + nf * 16 + fr) * 64 + swzk];
  };
  auto MF = [&](bf16x8* a, bf16x8* b) {
    __builtin_amdgcn_s_setprio(1);
#pragma unroll
    for (int mf = 0; mf < 8; ++mf)
#pragma unroll
      for (int nf = 0; nf < NF; ++nf)
        acc[mf][nf] = __builtin_amdgcn_mfma_f32_16x16x32_bf16(a[mf], b[nf], acc[mf][nf], 0, 0, 0);
    __builtin_amdgcn_s_setprio(0);
  };

  STAGE(0, 0);
  STAGE(1, 1);
  if constexpr (LW == 8) { asm volatile("s_waitcnt vmcnt(8)" ::: "memory"); }
  else                   { asm volatile("s_waitcnt vmcnt(6)" ::: "memory"); }
  __builtin_amdgcn_sched_barrier(0);
  __builtin_amdgcn_s_barrier();
  READ(0, 0, aA, bA);

  for (int t = 0; t < nt; ++t) {
    const int buf = t & 1;
    READ(buf, 1, aB, bB);                  // next k-step's operands, fly under MFMA
    __builtin_amdgcn_sched_barrier(0);
    MF(aA, bA);                            // compiler emits lgkmcnt(12) before first MFMA
    asm volatile("s_waitcnt lgkmcnt(0)" ::: "memory");
    __builtin_amdgcn_sched_barrier(0);
    __builtin_amdgcn_s_barrier();          // B1: all waves done reading buf_t
    if (t + 2 < nt) {
      STAGE(t + 2, buf);                   // overwrite buf_t with tile t+2
      if constexpr (LW == 8) { asm volatile("s_waitcnt vmcnt(8)" ::: "memory"); }
      else                   { asm volatile("s_waitcnt vmcnt(6)" ::: "memory"); }
    } else {
      asm volatile("s_waitcnt vmcnt(0)" ::: "memory");
    }
    __builtin_amdgcn_sched_barrier(0);
    __builtin_amdgcn_s_barrier();          // B2: tile t+1 fully landed (all waves)
    if (t + 1 < nt) READ(buf ^ 1, 0, aA, bA);  // (t+1, k0) operands under MF(aB,bB)
    __builtin_amdgcn_sched_barrier(0);
    MF(aB, bB);
  }

  // epilogue: 16x16x32 C-layout col=lane&15, row=(lane>>4)*4+r
#pragma unroll
  for (int mf = 0; mf < 8; ++mf)
#pragma unroll
    for (int nf = 0; nf < NF; ++nf) {
      const int col = col0 + wn * (TN / 4) + nf * 16 + fr;
#pragma unroll
      for (int r = 0; r < 4; ++r) {
        const int row = row0 + wm * 128 + mf * 16 + fq * 4 + r;
        C[(size_t)row * N + col] = (CT)acc[mf][nf][r];
      }
    }
}

// ---------------- in-place RoPE rotation on 64-wide rope slices ----------------
__global__ __launch_bounds__(256) void rope_kernel(
    bf16_t* __restrict__ base, int tokStride, int hshift, int posMask) {
  const long idx = (long)blockIdx.x * 8 + (threadIdx.x >> 5);  // tok*heads + h
  const int i = threadIdx.x & 31;
  const long tok = idx >> hshift;
  const int h = (int)(idx & ((1 << hshift) - 1));
  const int pos = (int)(tok & posMask);
  bf16_t* p = base + tok * (long)tokStride + h * 64;
  const float x1 = (float)p[i], x2 = (float)p[i + 32];
  const float invf = expf(-((float)i * (1.0f / 32.f)) * 9.210340371976184f);  // ln(10000)
  float sn, cs;
  sincosf((float)pos * invf, &sn, &cs);
  p[i]      = (bf16_t)(x1 * cs - x2 * sn);
  p[i + 32] = (bf16_t)(x1 * sn + x2 * cs);
}

// ---------------- sparse windowed attention: <=9 keys per query ----------------
__global__ __launch_bounds__(256) void attn_sparse(
    const bf16_t* __restrict__ qc, const bf16_t* __restrict__ kvc,
    const int* __restrict__ seg, bf16_t* __restrict__ out) {
  const int qrow = blockIdx.x * 4 + (threadIdx.x >> 6);  // b*LQ + qi
  const int lane = threadIdx.x & 63;
  const int h = lane >> 2, sub = lane & 3;
  const int b = qrow >> 12;  // / LQ
  const int s = seg[qrow];
  const int kl = max(0, s - 8);
  const float scale = 0.07216878364870322f;  // 1/sqrt(HD+R)

  float qnf[32], qrf[16];
  {
    const bf16_t* p = qc + (size_t)qrow * QCOMB + h * HD_ + sub * 32;
#pragma unroll
    for (int j = 0; j < 4; ++j) {
      bf16x8 t = *(const bf16x8*)(p + j * 8);
#pragma unroll
      for (int e = 0; e < 8; ++e) qnf[j * 8 + e] = (float)t[e];
    }
    const bf16_t* p2 = qc + (size_t)qrow * QCOMB + 2048 + h * R_ + sub * 16;
#pragma unroll
    for (int j = 0; j < 2; ++j) {
      bf16x8 t = *(const bf16x8*)(p2 + j * 8);
#pragma unroll
      for (int e = 0; e < 8; ++e) qrf[j * 8 + e] = (float)t[e];
    }
  }

  float sc[9];
#pragma unroll
  for (int kk = 0; kk < 9; ++kk) {
    const int kx = kl + kk;
    const bf16_t* kb = kvc + (size_t)(b * LK + kx) * KCOMB;
    float d = 0.f;
    const bf16_t* p = kb + h * HD_ + sub * 32;
#pragma unroll
    for (int j = 0; j < 4; ++j) {
      bf16x8 t = *(const bf16x8*)(p + j * 8);
#pragma unroll
      for (int e = 0; e < 8; ++e) d += qnf[j * 8 + e] * (float)t[e];
    }
    const bf16_t* p2 = kb + 4096 + sub * 16;
#pragma unroll
    for (int j = 0; j < 2; ++j) {
      bf16x8 t = *(const bf16x8*)(p2 + j * 8);
#pragma unroll
      for (int e = 0; e < 8; ++e) d += qrf[j * 8 + e] * (float)t[e];
    }
    d += __shfl_xor(d, 1);
    d += __shfl_xor(d, 2);
    sc[kk] = (kx <= s) ? d * scale : -1e30f;
  }
  float m = sc[0];
#pragma unroll
  for (int kk = 1; kk < 9; ++kk) m = fmaxf(m, sc[kk]);
  float sum = 0.f;
#pragma unroll
  for (int kk = 0; kk < 9; ++kk) { const float p = expf(sc[kk] - m); sc[kk] = p; sum += p; }
  const float inv = 1.f / sum;

  float o[32];
#pragma unroll
  for (int j = 0; j < 32; ++j) o[j] = 0.f;
#pragma unroll
  for (int kk = 0; kk < 9; ++kk) {
    const bf16_t* pv = kvc + (size_t)(b * LK + kl + kk) * KCOMB + 2048 + h * HD_ + sub * 32;
    const float p = sc[kk] * inv;
#pragma unroll
    for (int j = 0; j < 4; ++j) {
      bf16x8 t = *(const bf16x8*)(pv + j * 8);
#pragma unroll
      for (int e = 0; e < 8; ++e) o[j * 8 + e] += p * (float)t[e];
    }
  }
  bf16_t* po = out + (size_t)qrow * (H_ * HD_) + h * HD_ + sub * 32;
#pragma unroll
  for (int j = 0; j < 4; ++j) {
    bf16x8 t;
#pragma unroll
    for (int e = 0; e < 8; ++e) t[e] = (bf16_t)o[j * 8 + e];
    *(bf16x8*)(po + j * 8) = t;
  }
}

extern "C" void kernel_launch(void* const* d_in, const int* in_sizes, int n_in,
                              void* d_out, int out_size, void* d_ws, size_t ws_size,
                              hipStream_t stream) {
  const float* q     = (const float*)d_in[0];
  const float* kv    = (const float*)d_in[1];
  const int*   seg   = (const int*)d_in[2];
  const float* W_kvc = (const float*)d_in[3];
  const float* W_dq  = (const float*)d_in[4];
  const float* W_uq  = (const float*)d_in[5];
  const float* W_qr  = (const float*)d_in[6];
  const float* W_uk  = (const float*)d_in[7];
  const float* W_kr  = (const float*)d_in[8];
  const float* W_uv  = (const float*)d_in[9];
  const float* W_o   = (const float*)d_in[10];
  float* out = (float*)d_out;
  (void)in_sizes; (void)n_in; (void)out_size; (void)ws_size;

  char* ws = (char*)d_ws;
  size_t off = 0;
  auto alloc = [&](size_t bytes) {
    char* p = ws + off;
    off = (off + bytes + 255) & ~(size_t)255;
    return p;
  };
  bf16_t* q_bf    = (bf16_t*)alloc((size_t)B_ * LQ * QDIM * 2);   // reused as attn_o
  bf16_t* kv_bf   = (bf16_t*)alloc((size_t)B_ * LK * KVDIM * 2);
  bf16_t* WkvcT   = (bf16_t*)alloc((size_t)KVC_ * KVDIM * 2);
  bf16_t* WdqT    = (bf16_t*)alloc((size_t)QC_ * QDIM * 2);
  bf16_t* WuqrT   = (bf16_t*)alloc((size_t)QCOMB * QC_ * 2);      // [W_uq^T ; W_qr^T]
  bf16_t* WkvT    = (bf16_t*)alloc((size_t)KCOMB * KVC_ * 2);     // [W_uk^T ; W_uv^T ; W_kr^T ; pad]
  bf16_t* WoT     = (bf16_t*)alloc((size_t)QDIM * (H_ * HD_) * 2);
  bf16_t* kv_c    = (bf16_t*)alloc((size_t)B_ * LK * KVC_ * 2);
  bf16_t* q_c     = (bf16_t*)alloc((size_t)B_ * LQ * QC_ * 2);
  bf16_t* q_comb  = (bf16_t*)alloc((size_t)B_ * LQ * QCOMB * 2);
  bf16_t* kv_comb = (bf16_t*)alloc((size_t)B_ * LK * KCOMB * 2);
  bf16_t* attn_o  = q_bf;  // q_bf dead after q_c GEMM

  // ---- convert inputs to bf16 ----
  cvt_f32_bf16<<<4096, 256, 0, stream>>>(q, q_bf, (long)B_ * LQ * QDIM);
  cvt_f32_bf16<<<2048, 256, 0, stream>>>(kv, kv_bf, (long)B_ * LK * KVDIM);
  const dim3 tb(32, 8);
  transpose_cvt<<<dim3(KVC_ / 32, KVDIM / 32), tb, 0, stream>>>(W_kvc, WkvcT, KVDIM, KVC_);
  transpose_cvt<<<dim3(QC_ / 32, QDIM / 32), tb, 0, stream>>>(W_dq, WdqT, QDIM, QC_);
  transpose_cvt<<<dim3((H_ * HD_) / 32, QC_ / 32), tb, 0, stream>>>(W_uq, WuqrT, QC_, H_ * HD_);
  transpose_cvt<<<dim3((H_ * R_) / 32, QC_ / 32), tb, 0, stream>>>(
      W_qr, WuqrT + (size_t)(H_ * HD_) * QC_, QC_, H_ * R_);
  transpose_cvt<<<dim3((H_ * HD_) / 32, KVC_ / 32), tb, 0, stream>>>(W_uk, WkvT, KVC_, H_ * HD_);
  transpose_cvt<<<dim3((H_ * HD_) / 32, KVC_ / 32), tb, 0, stream>>>(
      W_uv, WkvT + (size_t)(H_ * HD_) * KVC_, KVC_, H_ * HD_);
  transpose_cvt<<<dim3(R_ / 32, KVC_ / 32), tb, 0, stream>>>(
      W_kr, WkvT + (size_t)2 * (H_ * HD_) * KVC_, KVC_, R_);
  transpose_cvt<<<dim3(QDIM / 32, (H_ * HD_) / 32), tb, 0, stream>>>(W_o, WoT, H_ * HD_, QDIM);

  // ---- projection GEMMs (C = A @ Bt^T) ----
  gemm_bt<bf16_t><<<dim3(KVC_ / 128, (B_ * LK) / 128), 256, 0, stream>>>(
      kv_bf, WkvcT, kv_c, B_ * LK, KVC_, KVDIM);
  gemm_big2<128, bf16_t><<<dim3(QC_ / 128, (B_ * LQ) / 256), 512, 0, stream>>>(
      q_bf, WdqT, q_c, B_ * LQ, QC_, QDIM);
  gemm_big2<256, bf16_t><<<dim3(QCOMB / 256, (B_ * LQ) / 256), 512, 0, stream>>>(
      q_c, WuqrT, q_comb, B_ * LQ, QCOMB, QC_);
  rope_kernel<<<(B_ * LQ * H_) / 8, 256, 0, stream>>>(q_comb + 2048, QCOMB, 4, LQ - 1);
  gemm_big2<128, bf16_t><<<dim3(KCOMB / 128, (B_ * LK) / 256), 512, 0, stream>>>(
      kv_c, WkvT, kv_comb, B_ * LK, KCOMB, KVC_);
  rope_kernel<<<(B_ * LK) / 8, 256, 0, stream>>>(kv_comb + 4096, KCOMB, 0, LK - 1);

  // ---- sparse attention (<=9 keys/query) ----
  attn_sparse<<<(B_ * LQ) / 4, 256, 0, stream>>>(q_comb, kv_comb, seg, attn_o);

  // ---- output projection ----
  gemm_big2<256, float><<<dim3(QDIM / 256, (B_ * LQ) / 256), 512, 0, stream>>>(
      attn_o, WoT, out, B_ * LQ, QDIM, H_ * HD_);
}

// Round 5
// 368.045 us; speedup vs baseline: 1.1507x; 1.0282x over previous
//
#include <hip/hip_runtime.h>
#include <math.h>

typedef __bf16 bf16_t;
typedef __bf16 bf16x8 __attribute__((ext_vector_type(8)));
typedef float f32x4 __attribute__((ext_vector_type(4)));

#define B_    2
#define LQ    4096
#define LK    1024
#define QDIM  2048
#define KVDIM 2048
#define H_    16
#define HD_   128
#define KVC_  512
#define QC_   768
#define R_    64

// fused row widths
#define QCOMB 3072   // [q_nope(2048) | q_rope(1024)]
#define KCOMB 4224   // [k_nope(2048) | v(2048) | k_rope(64) | pad(64)]

typedef __attribute__((address_space(1))) void gvoid_t;
typedef __attribute__((address_space(3))) void lvoid_t;

static __device__ __forceinline__ void gld_lds16(const void* g, void* l) {
  __builtin_amdgcn_global_load_lds((gvoid_t*)(void*)g, (lvoid_t*)l, 16, 0, 0);
}

// ---------------- fp32 -> bf16 convert (vectorized) ----------------
__global__ void cvt_f32_bf16(const float* __restrict__ in, bf16_t* __restrict__ out, long n) {
  long i = ((long)blockIdx.x * blockDim.x + threadIdx.x) * 8;
  const long stride = (long)gridDim.x * blockDim.x * 8;
  for (; i < n; i += stride) {
    float4 a = *(const float4*)(in + i);
    float4 b = *(const float4*)(in + i + 4);
    bf16x8 t;
    t[0] = (bf16_t)a.x; t[1] = (bf16_t)a.y; t[2] = (bf16_t)a.z; t[3] = (bf16_t)a.w;
    t[4] = (bf16_t)b.x; t[5] = (bf16_t)b.y; t[6] = (bf16_t)b.z; t[7] = (bf16_t)b.w;
    *(bf16x8*)(out + i) = t;
  }
}

// ---------------- transpose + convert: in (K x N) fp32 -> out (N x K) bf16 ----------------
__global__ void transpose_cvt(const float* __restrict__ in, bf16_t* __restrict__ out, int K, int N) {
  __shared__ float t[32][33];
  const int bx = blockIdx.x * 32, by = blockIdx.y * 32;
  const int x = threadIdx.x, y = threadIdx.y;
#pragma unroll
  for (int j = 0; j < 32; j += 8) {
    int k = by + y + j, nn = bx + x;
    if (k < K && nn < N) t[y + j][x] = in[(size_t)k * N + nn];
  }
  __syncthreads();
#pragma unroll
  for (int j = 0; j < 32; j += 8) {
    int nn = bx + y + j, k = by + x;
    if (nn < N && k < K) out[(size_t)nn * K + k] = (bf16_t)t[x][y + j];
  }
}

// ---------------- small-M bf16 MFMA GEMM (128x128, BK=64, 4 waves) ----------------
template <typename CT>
__global__ __launch_bounds__(256) void gemm_bt(
    const bf16_t* __restrict__ A, const bf16_t* __restrict__ Bt,
    CT* __restrict__ C, int M, int N, int K) {
  __shared__ __align__(16) bf16_t lA[128 * 64];
  __shared__ __align__(16) bf16_t lB[128 * 64];
  const int tid = threadIdx.x;
  const int wave = tid >> 6, lane = tid & 63;

  const int gx = gridDim.x, gy = gridDim.y;
  const int nwg = gx * gy;
  int bx, by;
  if (((nwg & 7) == 0) && ((gy & 7) == 0)) {
    const int orig = blockIdx.y * gx + blockIdx.x;
    const int wg = (orig & 7) * (nwg >> 3) + (orig >> 3);
    const int gxB = gx << 3;
    const int band = wg / gxB, rem = wg % gxB;
    bx = rem >> 3;
    by = (band << 3) + (rem & 7);
  } else {
    bx = blockIdx.x; by = blockIdx.y;
  }

  const int row0 = by * 128, col0 = bx * 128;
  const int wr = (wave >> 1) * 64, wc = (wave & 1) * 64;
  f32x4 acc[4][4] = {};
  const int kT = K >> 6;
  const int lr = lane >> 3;
  const int lc8 = (lane & 7) * 8;

  for (int kt = 0; kt < kT; ++kt) {
    const int k0 = kt << 6;
    __syncthreads();
#pragma unroll
    for (int j = 0; j < 4; ++j) {
      const int c = wave * 4 + j;
      const bf16_t* ga = A + (size_t)(row0 + c * 8 + lr) * K + k0 + lc8;
      gld_lds16(ga, &lA[c * 512]);
      const bf16_t* gb = Bt + (size_t)(col0 + c * 8 + lr) * K + k0 + lc8;
      gld_lds16(gb, &lB[c * 512]);
    }
    __syncthreads();
#pragma unroll
    for (int kk = 0; kk < 2; ++kk) {
      bf16x8 af[4], bfr[4];
      const int kc = kk * 32 + (lane >> 4) * 8;
      const int fr = lane & 15;
#pragma unroll
      for (int m = 0; m < 4; ++m)
        af[m] = *(const bf16x8*)&lA[(wr + m * 16 + fr) * 64 + kc];
#pragma unroll
      for (int n = 0; n < 4; ++n)
        bfr[n] = *(const bf16x8*)&lB[(wc + n * 16 + fr) * 64 + kc];
#pragma unroll
      for (int m = 0; m < 4; ++m)
#pragma unroll
        for (int n = 0; n < 4; ++n)
          acc[m][n] = __builtin_amdgcn_mfma_f32_16x16x32_bf16(af[m], bfr[n], acc[m][n], 0, 0, 0);
    }
  }
  const int fr = lane & 15, fq = lane >> 4;
#pragma unroll
  for (int m = 0; m < 4; ++m)
#pragma unroll
    for (int n = 0; n < 4; ++n) {
      const int col = col0 + wc + n * 16 + fr;
#pragma unroll
      for (int r = 0; r < 4; ++r) {
        const int row = row0 + wr + m * 16 + fq * 4 + r;
        C[(size_t)row * N + col] = (CT)acc[m][n][r];
      }
    }
}

// ---------------- big pipelined GEMM v2: BM=256, BN=TN, BK=64, 8 waves (2Mx4N) ----------------
template <int TN, typename CT>
__global__ __launch_bounds__(512, 2) void gemm_big2(
    const bf16_t* __restrict__ A, const bf16_t* __restrict__ Bt,
    CT* __restrict__ C, int M, int N, int K) {
  constexpr int NF = TN / 64;
  constexpr int LW = 4 + TN / 64;
  __shared__ __align__(16) bf16_t lA[2][256 * 64];
  __shared__ __align__(16) bf16_t lB[2][TN * 64];
  const int tid = threadIdx.x;
  const int w = tid >> 6, lane = tid & 63;

  const int gx = gridDim.x;
  const int nwg = gx * gridDim.y;
  const int orig = blockIdx.y * gx + blockIdx.x;
  const int wg = (orig & 7) * (nwg >> 3) + (orig >> 3);
  const int bx = wg % gx, by = wg / gx;

  const int row0 = by * 256, col0 = bx * TN;
  const int wm = w >> 2, wn = w & 3;
  const int lr = lane >> 3;
  const int kswz = ((lane & 7) ^ lr) * 8;
  const int nt = K >> 6;
  const int fr = lane & 15, fq = lane >> 4;

  auto STAGE = [&](int t, int buf) {
    const int k0 = t << 6;
#pragma unroll
    for (int j = 0; j < 4; ++j) {
      const int s = j * 8 + w;
      gld_lds16(A + (size_t)(row0 + s * 8 + lr) * K + k0 + kswz, &lA[buf][s * 512]);
    }
#pragma unroll
    for (int j = 0; j < TN / 64; ++j) {
      const int s = j * 8 + w;
      gld_lds16(Bt + (size_t)(col0 + s * 8 + lr) * K + k0 + kswz, &lB[buf][s * 512]);
    }
  };

  bf16x8 aA[8], bA[NF], aB[8], bB[NF];
  f32x4 acc[8][NF];
#pragma unroll
  for (int i = 0; i < 8; ++i)
#pragma unroll
    for (int j = 0; j < NF; ++j) acc[i][j] = f32x4{0.f, 0.f, 0.f, 0.f};

  auto READ = [&](int buf, int kk, bf16x8* a, bf16x8* b) {
    const int swzk = (kk * 32 + fq * 8) ^ ((fr & 7) << 3);
#pragma unroll
    for (int mf = 0; mf < 8; ++mf)
      a[mf] = *(const bf16x8*)&lA[buf][(wm * 128 + mf * 16 + fr) * 64 + swzk];
#pragma unroll
    for (int nf = 0; nf < NF; ++nf)
      b[nf] = *(const bf16x8*)&lB[buf][(wn * (TN / 4) + nf * 16 + fr) * 64 + swzk];
  };
  auto MF = [&](bf16x8* a, bf16x8* b) {
    __builtin_amdgcn_s_setprio(1);
#pragma unroll
    for (int mf = 0; mf < 8; ++mf)
#pragma unroll
      for (int nf = 0; nf < NF; ++nf)
        acc[mf][nf] = __builtin_amdgcn_mfma_f32_16x16x32_bf16(a[mf], b[nf], acc[mf][nf], 0, 0, 0);
    __builtin_amdgcn_s_setprio(0);
  };

  STAGE(0, 0);
  STAGE(1, 1);
  if constexpr (LW == 8) { asm volatile("s_waitcnt vmcnt(8)" ::: "memory"); }
  else                   { asm volatile("s_waitcnt vmcnt(6)" ::: "memory"); }
  __builtin_amdgcn_sched_barrier(0);
  __builtin_amdgcn_s_barrier();
  READ(0, 0, aA, bA);

  for (int t = 0; t < nt; ++t) {
    const int buf = t & 1;
    READ(buf, 1, aB, bB);
    __builtin_amdgcn_sched_barrier(0);
    MF(aA, bA);
    asm volatile("s_waitcnt lgkmcnt(0)" ::: "memory");
    __builtin_amdgcn_sched_barrier(0);
    __builtin_amdgcn_s_barrier();
    if (t + 2 < nt) {
      STAGE(t + 2, buf);
      if constexpr (LW == 8) { asm volatile("s_waitcnt vmcnt(8)" ::: "memory"); }
      else                   { asm volatile("s_waitcnt vmcnt(6)" ::: "memory"); }
    } else {
      asm volatile("s_waitcnt vmcnt(0)" ::: "memory");
    }
    __builtin_amdgcn_sched_barrier(0);
    __builtin_amdgcn_s_barrier();
    if (t + 1 < nt) READ(buf ^ 1, 0, aA, bA);
    __builtin_amdgcn_sched_barrier(0);
    MF(aB, bB);
  }

#pragma unroll
  for (int mf = 0; mf < 8; ++mf)
#pragma unroll
    for (int nf = 0; nf < NF; ++nf) {
      const int col = col0 + wn * (TN / 4) + nf * 16 + fr;
#pragma unroll
      for (int r = 0; r < 4; ++r) {
        const int row = row0 + wm * 128 + mf * 16 + fq * 4 + r;
        C[(size_t)row * N + col] = (CT)acc[mf][nf][r];
      }
    }
}

// ---------------- 8-phase GEMM (m201-template port): BM=BN=256, BK=64, 8 waves ----------------
// LDS 128 KiB = 2 buf x 2 half x 128x64 x (A,B). Per K-tile: 4 phases, each =
// {ds-read quadrant frags + stage 1 half-tile -> barrier -> lgkmcnt(0) -> 16 MFMA -> barrier}.
// Stage order per tile t: ph0:A0(t+1)->buf^1  ph1:A1(t+1)->buf^1  ph2:B0(t+2)->buf  ph3:B1(t+2)->buf.
// Safety: A-halves go to idle buffer (its reads drained end of tile t-1); B-half overwrites
// happen at ph2/ph3, after all B reads of tile t (issued ph0/ph1, drained by each wave's
// lgkmcnt(0) before its ph1 MFMA, ordered block-wide by ph1's closing barrier).
// vmcnt(4) once per K-tile at ph3 (newest 2 half-tiles in flight) -> tile t+1 landed.
#define SWZK_(ks) (((ks) * 32 + fq * 8) ^ ((fr & 7) << 3))
#define RD_A(buf, q) { _Pragma("unroll") for (int mf = 0; mf < 4; ++mf) { \
    ar[mf][0] = *(const bf16x8*)&lA[buf][wm][((q) * 64 + mf * 16 + fr) * 64 + SWZK_(0)]; \
    ar[mf][1] = *(const bf16x8*)&lA[buf][wm][((q) * 64 + mf * 16 + fr) * 64 + SWZK_(1)]; } }
#define RD_B(buf, nq) { _Pragma("unroll") for (int nf = 0; nf < 2; ++nf) { \
    br[nq][nf][0] = *(const bf16x8*)&lB[buf][wbh][(wbr + (nq) * 32 + nf * 16 + fr) * 64 + SWZK_(0)]; \
    br[nq][nf][1] = *(const bf16x8*)&lB[buf][wbh][(wbr + (nq) * 32 + nf * 16 + fr) * 64 + SWZK_(1)]; } }
#define MFMA_Q(mq, nq) { __builtin_amdgcn_s_setprio(1); \
  _Pragma("unroll") for (int mf = 0; mf < 4; ++mf) \
  _Pragma("unroll") for (int nf = 0; nf < 2; ++nf) { \
    acc[(mq)*4+mf][(nq)*2+nf] = __builtin_amdgcn_mfma_f32_16x16x32_bf16(ar[mf][0], br[nq][nf][0], acc[(mq)*4+mf][(nq)*2+nf], 0, 0, 0); \
    acc[(mq)*4+mf][(nq)*2+nf] = __builtin_amdgcn_mfma_f32_16x16x32_bf16(ar[mf][1], br[nq][nf][1], acc[(mq)*4+mf][(nq)*2+nf], 0, 0, 0); } \
  __builtin_amdgcn_s_setprio(0); }
#define SBAR_ __builtin_amdgcn_sched_barrier(0)
#define HBAR_ __builtin_amdgcn_s_barrier()
#define LGK0_ asm volatile("s_waitcnt lgkmcnt(0)" ::: "memory")

template <typename CT>
__global__ __launch_bounds__(512, 2) void gemm_8ph(
    const bf16_t* __restrict__ A, const bf16_t* __restrict__ Bt,
    CT* __restrict__ C, int M, int N, int K) {
  __shared__ __align__(16) bf16_t lA[2][2][128 * 64];
  __shared__ __align__(16) bf16_t lB[2][2][128 * 64];
  const int tid = threadIdx.x;
  const int w = tid >> 6, lane = tid & 63;

  const int gx = gridDim.x;
  const int nwg = gx * gridDim.y;
  const int orig = blockIdx.y * gx + blockIdx.x;
  const int wg = (orig & 7) * (nwg >> 3) + (orig >> 3);
  const int bx = wg % gx, by = wg / gx;

  const int row0 = by * 256, col0 = bx * 256;
  const int wm = w >> 2, wn = w & 3;          // 2M x 4N waves, wave tile 128x64
  const int lr = lane >> 3;
  const int kswz = ((lane & 7) ^ lr) * 8;     // pre-swizzled global k-offset
  const int nt = K >> 6;
  const int fr = lane & 15, fq = lane >> 4;
  const int wbh = wn >> 1;                    // B LDS half this wave reads
  const int wbr = (wn & 1) * 64;              // row base within that half

  auto stA = [&](int t, int h, int buf) {     // stage A half-tile (128 rows x 64 k)
    const bf16_t* g = A + (size_t)(row0 + h * 128 + w * 8 + lr) * K + (t << 6) + kswz;
    gld_lds16(g, &lA[buf][h][w * 8 * 64]);
    gld_lds16(g + (size_t)64 * K, &lA[buf][h][(64 + w * 8) * 64]);
  };
  auto stB = [&](int t, int h, int buf) {
    const bf16_t* g = Bt + (size_t)(col0 + h * 128 + w * 8 + lr) * K + (t << 6) + kswz;
    gld_lds16(g, &lB[buf][h][w * 8 * 64]);
    gld_lds16(g + (size_t)64 * K, &lB[buf][h][(64 + w * 8) * 64]);
  };

  bf16x8 ar[4][2], br[2][2][2];   // A quad (reused across 2 phases), both B quads kept
  f32x4 acc[8][4];
#pragma unroll
  for (int i = 0; i < 8; ++i)
#pragma unroll
    for (int j = 0; j < 4; ++j) acc[i][j] = f32x4{0.f, 0.f, 0.f, 0.f};

  // prologue: tile 0 fully + B halves of tile 1 (A halves of tile 1 staged in tile 0's ph0/ph1)
  stA(0, 0, 0); stA(0, 1, 0); stB(0, 0, 0); stB(0, 1, 0);
  stB(1, 0, 1); stB(1, 1, 1);
  asm volatile("s_waitcnt vmcnt(4)" ::: "memory");  // tile 0's 4 halves landed
  SBAR_; HBAR_;

  for (int t = 0; t < nt; ++t) {
    const int buf = t & 1;
    // ---- ph0: read A(m0)+B(n0); stage A0(t+1) ----
    SBAR_;
    RD_A(buf, 0); RD_B(buf, 0);
    if (t + 1 < nt) stA(t + 1, 0, buf ^ 1);
    SBAR_; HBAR_; LGK0_; SBAR_;
    MFMA_Q(0, 0);
    SBAR_; HBAR_;
    // ---- ph1: read B(n1); stage A1(t+1) ----
    SBAR_;
    RD_B(buf, 1);
    if (t + 1 < nt) stA(t + 1, 1, buf ^ 1);
    SBAR_; HBAR_; LGK0_; SBAR_;
    MFMA_Q(0, 1);
    SBAR_; HBAR_;
    // ---- ph2: read A(m1); stage B0(t+2) over consumed B0 ----
    SBAR_;
    RD_A(buf, 1);
    if (t + 2 < nt) stB(t + 2, 0, buf);
    SBAR_; HBAR_; LGK0_; SBAR_;
    MFMA_Q(1, 1);
    SBAR_; HBAR_;
    // ---- ph3: no reads (B(n0) held in regs); stage B1(t+2); counted vmcnt ----
    SBAR_;
    if (t + 2 < nt) {
      stB(t + 2, 1, buf);
      asm volatile("s_waitcnt vmcnt(4)" ::: "memory");  // all of tile t+1 landed
    } else {
      asm volatile("s_waitcnt vmcnt(0)" ::: "memory");  // drain tail
    }
    SBAR_; HBAR_; SBAR_;
    MFMA_Q(1, 0);
    SBAR_; HBAR_;
  }

  // epilogue: 16x16x32 C-layout col=lane&15, row=(lane>>4)*4+r
#pragma unroll
  for (int mfg = 0; mfg < 8; ++mfg)
#pragma unroll
    for (int nfg = 0; nfg < 4; ++nfg) {
      const int col = col0 + wn * 64 + (nfg >> 1) * 32 + (nfg & 1) * 16 + fr;
#pragma unroll
      for (int r = 0; r < 4; ++r) {
        const int row = row0 + wm * 128 + mfg * 16 + fq * 4 + r;
        C[(size_t)row * N + col] = (CT)acc[mfg][nfg][r];
      }
    }
}

// ---------------- in-place RoPE rotation on 64-wide rope slices ----------------
__global__ __launch_bounds__(256) void rope_kernel(
    bf16_t* __restrict__ base, int tokStride, int hshift, int posMask) {
  const long idx = (long)blockIdx.x * 8 + (threadIdx.x >> 5);  // tok*heads + h
  const int i = threadIdx.x & 31;
  const long tok = idx >> hshift;
  const int h = (int)(idx & ((1 << hshift) - 1));
  const int pos = (int)(tok & posMask);
  bf16_t* p = base + tok * (long)tokStride + h * 64;
  const float x1 = (float)p[i], x2 = (float)p[i + 32];
  const float invf = expf(-((float)i * (1.0f / 32.f)) * 9.210340371976184f);  // ln(10000)
  float sn, cs;
  sincosf((float)pos * invf, &sn, &cs);
  p[i]      = (bf16_t)(x1 * cs - x2 * sn);
  p[i + 32] = (bf16_t)(x1 * sn + x2 * cs);
}

// ---------------- sparse windowed attention: <=9 keys per query ----------------
__global__ __launch_bounds__(256) void attn_sparse(
    const bf16_t* __restrict__ qc, const bf16_t* __restrict__ kvc,
    const int* __restrict__ seg, bf16_t* __restrict__ out) {
  const int qrow = blockIdx.x * 4 + (threadIdx.x >> 6);  // b*LQ + qi
  const int lane = threadIdx.x & 63;
  const int h = lane >> 2, sub = lane & 3;
  const int b = qrow >> 12;  // / LQ
  const int s = seg[qrow];
  const int kl = max(0, s - 8);
  const float scale = 0.07216878364870322f;  // 1/sqrt(HD+R)

  float qnf[32], qrf[16];
  {
    const bf16_t* p = qc + (size_t)qrow * QCOMB + h * HD_ + sub * 32;
#pragma unroll
    for (int j = 0; j < 4; ++j) {
      bf16x8 t = *(const bf16x8*)(p + j * 8);
#pragma unroll
      for (int e = 0; e < 8; ++e) qnf[j * 8 + e] = (float)t[e];
    }
    const bf16_t* p2 = qc + (size_t)qrow * QCOMB + 2048 + h * R_ + sub * 16;
#pragma unroll
    for (int j = 0; j < 2; ++j) {
      bf16x8 t = *(const bf16x8*)(p2 + j * 8);
#pragma unroll
      for (int e = 0; e < 8; ++e) qrf[j * 8 + e] = (float)t[e];
    }
  }

  float sc[9];
#pragma unroll
  for (int kk = 0; kk < 9; ++kk) {
    const int kx = kl + kk;
    const bf16_t* kb = kvc + (size_t)(b * LK + kx) * KCOMB;
    float d = 0.f;
    const bf16_t* p = kb + h * HD_ + sub * 32;
#pragma unroll
    for (int j = 0; j < 4; ++j) {
      bf16x8 t = *(const bf16x8*)(p + j * 8);
#pragma unroll
      for (int e = 0; e < 8; ++e) d += qnf[j * 8 + e] * (float)t[e];
    }
    const bf16_t* p2 = kb + 4096 + sub * 16;
#pragma unroll
    for (int j = 0; j < 2; ++j) {
      bf16x8 t = *(const bf16x8*)(p2 + j * 8);
#pragma unroll
      for (int e = 0; e < 8; ++e) d += qrf[j * 8 + e] * (float)t[e];
    }
    d += __shfl_xor(d, 1);
    d += __shfl_xor(d, 2);
    sc[kk] = (kx <= s) ? d * scale : -1e30f;
  }
  float m = sc[0];
#pragma unroll
  for (int kk = 1; kk < 9; ++kk) m = fmaxf(m, sc[kk]);
  float sum = 0.f;
#pragma unroll
  for (int kk = 0; kk < 9; ++kk) { const float p = expf(sc[kk] - m); sc[kk] = p; sum += p; }
  const float inv = 1.f / sum;

  float o[32];
#pragma unroll
  for (int j = 0; j < 32; ++j) o[j] = 0.f;
#pragma unroll
  for (int kk = 0; kk < 9; ++kk) {
    const bf16_t* pv = kvc + (size_t)(b * LK + kl + kk) * KCOMB + 2048 + h * HD_ + sub * 32;
    const float p = sc[kk] * inv;
#pragma unroll
    for (int j = 0; j < 4; ++j) {
      bf16x8 t = *(const bf16x8*)(pv + j * 8);
#pragma unroll
      for (int e = 0; e < 8; ++e) o[j * 8 + e] += p * (float)t[e];
    }
  }
  bf16_t* po = out + (size_t)qrow * (H_ * HD_) + h * HD_ + sub * 32;
#pragma unroll
  for (int j = 0; j < 4; ++j) {
    bf16x8 t;
#pragma unroll
    for (int e = 0; e < 8; ++e) t[e] = (bf16_t)o[j * 8 + e];
    *(bf16x8*)(po + j * 8) = t;
  }
}

extern "C" void kernel_launch(void* const* d_in, const int* in_sizes, int n_in,
                              void* d_out, int out_size, void* d_ws, size_t ws_size,
                              hipStream_t stream) {
  const float* q     = (const float*)d_in[0];
  const float* kv    = (const float*)d_in[1];
  const int*   seg   = (const int*)d_in[2];
  const float* W_kvc = (const float*)d_in[3];
  const float* W_dq  = (const float*)d_in[4];
  const float* W_uq  = (const float*)d_in[5];
  const float* W_qr  = (const float*)d_in[6];
  const float* W_uk  = (const float*)d_in[7];
  const float* W_kr  = (const float*)d_in[8];
  const float* W_uv  = (const float*)d_in[9];
  const float* W_o   = (const float*)d_in[10];
  float* out = (float*)d_out;
  (void)in_sizes; (void)n_in; (void)out_size; (void)ws_size;

  char* ws = (char*)d_ws;
  size_t off = 0;
  auto alloc = [&](size_t bytes) {
    char* p = ws + off;
    off = (off + bytes + 255) & ~(size_t)255;
    return p;
  };
  bf16_t* q_bf    = (bf16_t*)alloc((size_t)B_ * LQ * QDIM * 2);   // reused as attn_o
  bf16_t* kv_bf   = (bf16_t*)alloc((size_t)B_ * LK * KVDIM * 2);
  bf16_t* WkvcT   = (bf16_t*)alloc((size_t)KVC_ * KVDIM * 2);
  bf16_t* WdqT    = (bf16_t*)alloc((size_t)QC_ * QDIM * 2);
  bf16_t* WuqrT   = (bf16_t*)alloc((size_t)QCOMB * QC_ * 2);      // [W_uq^T ; W_qr^T]
  bf16_t* WkvT    = (bf16_t*)alloc((size_t)KCOMB * KVC_ * 2);     // [W_uk^T ; W_uv^T ; W_kr^T ; pad]
  bf16_t* WoT     = (bf16_t*)alloc((size_t)QDIM * (H_ * HD_) * 2);
  bf16_t* kv_c    = (bf16_t*)alloc((size_t)B_ * LK * KVC_ * 2);
  bf16_t* q_c     = (bf16_t*)alloc((size_t)B_ * LQ * QC_ * 2);
  bf16_t* q_comb  = (bf16_t*)alloc((size_t)B_ * LQ * QCOMB * 2);
  bf16_t* kv_comb = (bf16_t*)alloc((size_t)B_ * LK * KCOMB * 2);
  bf16_t* attn_o  = q_bf;  // q_bf dead after q_c GEMM

  // ---- convert inputs to bf16 ----
  cvt_f32_bf16<<<4096, 256, 0, stream>>>(q, q_bf, (long)B_ * LQ * QDIM);
  cvt_f32_bf16<<<2048, 256, 0, stream>>>(kv, kv_bf, (long)B_ * LK * KVDIM);
  const dim3 tb(32, 8);
  transpose_cvt<<<dim3(KVC_ / 32, KVDIM / 32), tb, 0, stream>>>(W_kvc, WkvcT, KVDIM, KVC_);
  transpose_cvt<<<dim3(QC_ / 32, QDIM / 32), tb, 0, stream>>>(W_dq, WdqT, QDIM, QC_);
  transpose_cvt<<<dim3((H_ * HD_) / 32, QC_ / 32), tb, 0, stream>>>(W_uq, WuqrT, QC_, H_ * HD_);
  transpose_cvt<<<dim3((H_ * R_) / 32, QC_ / 32), tb, 0, stream>>>(
      W_qr, WuqrT + (size_t)(H_ * HD_) * QC_, QC_, H_ * R_);
  transpose_cvt<<<dim3((H_ * HD_) / 32, KVC_ / 32), tb, 0, stream>>>(W_uk, WkvT, KVC_, H_ * HD_);
  transpose_cvt<<<dim3((H_ * HD_) / 32, KVC_ / 32), tb, 0, stream>>>(
      W_uv, WkvT + (size_t)(H_ * HD_) * KVC_, KVC_, H_ * HD_);
  transpose_cvt<<<dim3(R_ / 32, KVC_ / 32), tb, 0, stream>>>(
      W_kr, WkvT + (size_t)2 * (H_ * HD_) * KVC_, KVC_, R_);
  transpose_cvt<<<dim3(QDIM / 32, (H_ * HD_) / 32), tb, 0, stream>>>(W_o, WoT, H_ * HD_, QDIM);

  // ---- projection GEMMs (C = A @ Bt^T) ----
  gemm_bt<bf16_t><<<dim3(KVC_ / 128, (B_ * LK) / 128), 256, 0, stream>>>(
      kv_bf, WkvcT, kv_c, B_ * LK, KVC_, KVDIM);
  gemm_big2<128, bf16_t><<<dim3(QC_ / 128, (B_ * LQ) / 256), 512, 0, stream>>>(
      q_bf, WdqT, q_c, B_ * LQ, QC_, QDIM);
  gemm_8ph<bf16_t><<<dim3(QCOMB / 256, (B_ * LQ) / 256), 512, 0, stream>>>(
      q_c, WuqrT, q_comb, B_ * LQ, QCOMB, QC_);
  rope_kernel<<<(B_ * LQ * H_) / 8, 256, 0, stream>>>(q_comb + 2048, QCOMB, 4, LQ - 1);
  gemm_big2<128, bf16_t><<<dim3(KCOMB / 128, (B_ * LK) / 256), 512, 0, stream>>>(
      kv_c, WkvT, kv_comb, B_ * LK, KCOMB, KVC_);
  rope_kernel<<<(B_ * LK) / 8, 256, 0, stream>>>(kv_comb + 4096, KCOMB, 0, LK - 1);

  // ---- sparse attention (<=9 keys/query) ----
  attn_sparse<<<(B_ * LQ) / 4, 256, 0, stream>>>(q_comb, kv_comb, seg, attn_o);

  // ---- output projection ----
  gemm_8ph<float><<<dim3(QDIM / 256, (B_ * LQ) / 256), 512, 0, stream>>>(
      attn_o, WoT, out, B_ * LQ, QDIM, H_ * HD_);
}